// Round 1
// baseline (1018.884 us; speedup 1.0000x reference)
//
#include <hip/hip_runtime.h>
#include <math.h>

#define HH 2048
#define WW 2048
#define HWSZ (HH*WW)
#define RMIN 7
#define RBOX 60
#define NBINS 8192
#define KTOP 4194
#define OMEGA 0.95f
#define T0C 0.1f
#define GFEPS 1e-4f

struct UdcpState {
    int hist[NBINS];
    int dcmax_bits;
    float tau;
    int A_bits[3];
};

// ---------- prep: minGB + grayscale guide ----------
__global__ void k_prep(const float* __restrict__ x, float* __restrict__ mgb,
                       float* __restrict__ guide) {
    int i = blockIdx.x * blockDim.x + threadIdx.x;
    float R = x[i], G = x[HWSZ + i], B = x[2 * HWSZ + i];
    mgb[i] = fminf(G, B);
    guide[i] = 0.299f * R + 0.587f * G + 0.114f * B;
}

// ---------- separable 15-tap min filters ----------
__global__ void k_minv(const float* __restrict__ in, float* __restrict__ out) {
    int i = blockIdx.x * blockDim.x + threadIdx.x;
    int y = i >> 11, xx = i & (WW - 1);
    int y0 = max(y - RMIN, 0), y1 = min(y + RMIN, HH - 1);
    float m = 1e30f;
    for (int yy = y0; yy <= y1; ++yy) m = fminf(m, in[yy * WW + xx]);
    out[i] = m;
}

__global__ void k_minh(const float* __restrict__ in, float* __restrict__ out) {
    int i = blockIdx.x * blockDim.x + threadIdx.x;
    int y = i >> 11, xx = i & (WW - 1);
    int x0 = max(xx - RMIN, 0), x1 = min(xx + RMIN, WW - 1);
    const float* row = in + y * WW;
    float m = 1e30f;
    for (int j = x0; j <= x1; ++j) m = fminf(m, row[j]);
    out[i] = m;
}

// horizontal min fused with t = 1 - omega*min
__global__ void k_minh_t(const float* __restrict__ in, float* __restrict__ out) {
    int i = blockIdx.x * blockDim.x + threadIdx.x;
    int y = i >> 11, xx = i & (WW - 1);
    int x0 = max(xx - RMIN, 0), x1 = min(xx + RMIN, WW - 1);
    const float* row = in + y * WW;
    float m = 1e30f;
    for (int j = x0; j <= x1; ++j) m = fminf(m, row[j]);
    out[i] = 1.0f - OMEGA * m;
}

// ---------- dark-channel max (for histogram range) ----------
__global__ void k_dcmax(const float* __restrict__ dc, UdcpState* st) {
    __shared__ float red[256];
    float m = 0.f;
    for (int i = blockIdx.x * blockDim.x + threadIdx.x; i < HWSZ;
         i += gridDim.x * blockDim.x)
        m = fmaxf(m, dc[i]);
    red[threadIdx.x] = m;
    __syncthreads();
    for (int s = 128; s > 0; s >>= 1) {
        if (threadIdx.x < s)
            red[threadIdx.x] = fmaxf(red[threadIdx.x], red[threadIdx.x + s]);
        __syncthreads();
    }
    if (threadIdx.x == 0) atomicMax(&st->dcmax_bits, __float_as_int(red[0]));
}

// ---------- histogram of dc over [0, dcmax] ----------
__global__ void k_hist(const float* __restrict__ dc, UdcpState* st) {
    __shared__ int h[NBINS];
    for (int j = threadIdx.x; j < NBINS; j += blockDim.x) h[j] = 0;
    __syncthreads();
    float dmax = __int_as_float(st->dcmax_bits);
    float scale = dmax > 0.f ? (float)NBINS / dmax : 0.f;
    for (int i = blockIdx.x * blockDim.x + threadIdx.x; i < HWSZ;
         i += gridDim.x * blockDim.x) {
        int b = (int)(dc[i] * scale);
        if (b > NBINS - 1) b = NBINS - 1;
        atomicAdd(&h[b], 1);
    }
    __syncthreads();
    for (int j = threadIdx.x; j < NBINS; j += blockDim.x) {
        int v = h[j];
        if (v) atomicAdd(&st->hist[j], v);
    }
}

// ---------- find k-th-largest bin lower edge ----------
__global__ void k_tau(UdcpState* st) {
    __shared__ int csum[256];
    int tid = threadIdx.x;
    int hi = NBINS - 1 - 32 * tid;
    int local = 0;
    for (int k = 0; k < 32; ++k) local += st->hist[hi - k];
    csum[tid] = local;
    __syncthreads();
    if (tid == 0) {
        float dmax = __int_as_float(st->dcmax_bits);
        int cum = 0;
        float tau = 0.f;
        bool done = false;
        for (int c = 0; c < 256 && !done; ++c) {
            if (cum + csum[c] >= KTOP) {
                int h2 = NBINS - 1 - 32 * c;
                int cc = cum;
                for (int k = 0; k < 32; ++k) {
                    cc += st->hist[h2 - k];
                    if (cc >= KTOP) {
                        tau = (float)(h2 - k) * dmax / (float)NBINS;
                        done = true;
                        break;
                    }
                }
            } else {
                cum += csum[c];
            }
        }
        st->tau = tau;
    }
}

// ---------- atmospheric light: per-channel max over dc >= tau ----------
__global__ void k_A(const float* __restrict__ dc, const float* __restrict__ x,
                    UdcpState* st) {
    int i = blockIdx.x * blockDim.x + threadIdx.x;
    float tau = st->tau;
    if (dc[i] >= tau) {
        atomicMax(&st->A_bits[0], __float_as_int(x[i]));
        atomicMax(&st->A_bits[1], __float_as_int(x[HWSZ + i]));
        atomicMax(&st->A_bits[2], __float_as_int(x[2 * HWSZ + i]));
    }
}

// ---------- normalized min(G/A1, B/A2) ----------
__global__ void k_s(const float* __restrict__ x, const UdcpState* st,
                    float* __restrict__ s) {
    int i = blockIdx.x * blockDim.x + threadIdx.x;
    float A1 = __int_as_float(st->A_bits[1]);
    float A2 = __int_as_float(st->A_bits[2]);
    s[i] = fminf(x[HWSZ + i] / A1, x[2 * HWSZ + i] / A2);
}

// ---------- horizontal 121-box on 4 fields (I, p, I*p, I*I) ----------
__global__ void k_boxh4(const float* __restrict__ g, const float* __restrict__ t,
                        float* __restrict__ hg, float* __restrict__ ht,
                        float* __restrict__ hgt, float* __restrict__ hgg) {
    int i = blockIdx.x * blockDim.x + threadIdx.x;
    int y = i >> 11, xx = i & (WW - 1);
    int x0 = max(xx - RBOX, 0), x1 = min(xx + RBOX, WW - 1);
    const float* gr = g + y * WW;
    const float* tr = t + y * WW;
    float sg = 0.f, stt = 0.f, sgt = 0.f, sgg = 0.f;
    for (int j = x0; j <= x1; ++j) {
        float lg = gr[j], lt = tr[j];
        sg += lg;
        stt += lt;
        sgt += lg * lt;
        sgg += lg * lg;
    }
    hg[i] = sg;
    ht[i] = stt;
    hgt[i] = sgt;
    hgg[i] = sgg;
}

// ---------- vertical 121-box on 4 fields + a/b pointwise ----------
__global__ void k_boxv4ab(const float* __restrict__ hg, const float* __restrict__ ht,
                          const float* __restrict__ hgt, const float* __restrict__ hgg,
                          float* __restrict__ a, float* __restrict__ b) {
    int i = blockIdx.x * blockDim.x + threadIdx.x;
    int y = i >> 11, xx = i & (WW - 1);
    int y0 = max(y - RBOX, 0), y1 = min(y + RBOX, HH - 1);
    float sg = 0.f, stt = 0.f, sgt = 0.f, sgg = 0.f;
    for (int yy = y0; yy <= y1; ++yy) {
        int j = yy * WW + xx;
        sg += hg[j];
        stt += ht[j];
        sgt += hgt[j];
        sgg += hgg[j];
    }
    float cy = (float)(y1 - y0 + 1);
    float cx = (float)(min(xx + RBOX, WW - 1) - max(xx - RBOX, 0) + 1);
    float inv = 1.0f / (cy * cx);
    float mI = sg * inv, mp = stt * inv;
    float cov = sgt * inv - mI * mp;
    float var = sgg * inv - mI * mI;
    float av = cov / (var + GFEPS);
    a[i] = av;
    b[i] = mp - av * mI;
}

// ---------- horizontal 121-box on 2 fields (a, b) ----------
__global__ void k_boxh2(const float* __restrict__ a, const float* __restrict__ b,
                        float* __restrict__ ha, float* __restrict__ hb) {
    int i = blockIdx.x * blockDim.x + threadIdx.x;
    int y = i >> 11, xx = i & (WW - 1);
    int x0 = max(xx - RBOX, 0), x1 = min(xx + RBOX, WW - 1);
    const float* ar = a + y * WW;
    const float* br = b + y * WW;
    float sa = 0.f, sb = 0.f;
    for (int j = x0; j <= x1; ++j) {
        sa += ar[j];
        sb += br[j];
    }
    ha[i] = sa;
    hb[i] = sb;
}

// ---------- vertical 121-box on (a,b) + radiance recovery ----------
__global__ void k_final(const float* __restrict__ ha, const float* __restrict__ hb,
                        const float* __restrict__ g, const float* __restrict__ x,
                        const UdcpState* st, float* __restrict__ out) {
    int i = blockIdx.x * blockDim.x + threadIdx.x;
    int y = i >> 11, xx = i & (WW - 1);
    int y0 = max(y - RBOX, 0), y1 = min(y + RBOX, HH - 1);
    float sa = 0.f, sb = 0.f;
    for (int yy = y0; yy <= y1; ++yy) {
        int j = yy * WW + xx;
        sa += ha[j];
        sb += hb[j];
    }
    float cy = (float)(y1 - y0 + 1);
    float cx = (float)(min(xx + RBOX, WW - 1) - max(xx - RBOX, 0) + 1);
    float inv = 1.0f / (cy * cx);
    float q = sa * inv * g[i] + sb * inv;
    float tr = fmaxf(q, T0C);
    float invt = 1.0f / tr;
    float A0 = __int_as_float(st->A_bits[0]);
    float A1 = __int_as_float(st->A_bits[1]);
    float A2 = __int_as_float(st->A_bits[2]);
    float J0 = (x[i] - A0) * invt + A0;
    float J1 = (x[HWSZ + i] - A1) * invt + A1;
    float J2 = (x[2 * HWSZ + i] - A2) * invt + A2;
    out[i] = fminf(fmaxf(J0, 0.f), 1.f);
    out[HWSZ + i] = fminf(fmaxf(J1, 0.f), 1.f);
    out[2 * HWSZ + i] = fminf(fmaxf(J2, 0.f), 1.f);
}

extern "C" void kernel_launch(void* const* d_in, const int* in_sizes, int n_in,
                              void* d_out, int out_size, void* d_ws, size_t ws_size,
                              hipStream_t stream) {
    const float* x = (const float*)d_in[0];
    float* out = (float*)d_out;
    char* ws = (char*)d_ws;
    UdcpState* st = (UdcpState*)ws;
    float* B0 = (float*)(ws + 65536);
    float* B1 = B0 + HWSZ;
    float* B2 = B1 + HWSZ;
    float* B3 = B2 + HWSZ;
    float* B4 = B3 + HWSZ;
    float* B5 = B4 + HWSZ;
    float* B6 = B5 + HWSZ;

    hipMemsetAsync(st, 0, sizeof(UdcpState), stream);

    const int NB = HWSZ / 256;
    dim3 blk(256);

    // dark channel
    k_prep<<<NB, blk, 0, stream>>>(x, B0, B3);       // B0 = min(G,B), B3 = guide
    k_minv<<<NB, blk, 0, stream>>>(B0, B1);
    k_minh<<<NB, blk, 0, stream>>>(B1, B2);          // B2 = dc

    // atmospheric light
    k_dcmax<<<2048, blk, 0, stream>>>(B2, st);
    k_hist<<<256, blk, 0, stream>>>(B2, st);
    k_tau<<<1, blk, 0, stream>>>(st);
    k_A<<<NB, blk, 0, stream>>>(B2, x, st);

    // transmission
    k_s<<<NB, blk, 0, stream>>>(x, st, B0);          // B0 = min(G/A1, B/A2)
    k_minv<<<NB, blk, 0, stream>>>(B0, B1);
    k_minh_t<<<NB, blk, 0, stream>>>(B1, B0);        // B0 = t

    // guided filter
    k_boxh4<<<NB, blk, 0, stream>>>(B3, B0, B1, B2, B4, B5);
    k_boxv4ab<<<NB, blk, 0, stream>>>(B1, B2, B4, B5, B6, B0);  // B6 = a, B0 = b
    k_boxh2<<<NB, blk, 0, stream>>>(B6, B0, B1, B2);
    k_final<<<NB, blk, 0, stream>>>(B1, B2, B3, x, st, out);
}

// Round 2
// 521.218 us; speedup vs baseline: 1.9548x; 1.9548x over previous
//
#include <hip/hip_runtime.h>
#include <math.h>

#define HH 2048
#define WW 2048
#define HWSZ (HH*WW)
#define RMIN 7
#define RBOX 60
#define NBINS 8192
#define KTOP 4194
#define OMEGA 0.95f
#define T0C 0.1f
#define GFEPS 1e-4f
#define SEG 64

struct UdcpState {
    int hist[NBINS];
    int dcmax_bits;
    float tau;
    int A_bits[3];
};

// ---------- prep: minGB + grayscale guide ----------
__global__ void k_prep(const float* __restrict__ x, float* __restrict__ mgb,
                       float* __restrict__ guide) {
    int i = blockIdx.x * blockDim.x + threadIdx.x;
    float R = x[i], G = x[HWSZ + i], B = x[2 * HWSZ + i];
    mgb[i] = fminf(G, B);
    guide[i] = 0.299f * R + 0.587f * G + 0.114f * B;
}

// ---------- separable 15-tap min filters ----------
__global__ void k_minv(const float* __restrict__ in, float* __restrict__ out) {
    int i = blockIdx.x * blockDim.x + threadIdx.x;
    int y = i >> 11, xx = i & (WW - 1);
    int y0 = max(y - RMIN, 0), y1 = min(y + RMIN, HH - 1);
    float m = 1e30f;
    for (int yy = y0; yy <= y1; ++yy) m = fminf(m, in[yy * WW + xx]);
    out[i] = m;
}

__global__ void k_minh(const float* __restrict__ in, float* __restrict__ out) {
    int i = blockIdx.x * blockDim.x + threadIdx.x;
    int y = i >> 11, xx = i & (WW - 1);
    int x0 = max(xx - RMIN, 0), x1 = min(xx + RMIN, WW - 1);
    const float* row = in + y * WW;
    float m = 1e30f;
    for (int j = x0; j <= x1; ++j) m = fminf(m, row[j]);
    out[i] = m;
}

// horizontal min fused with t = 1 - omega*min
__global__ void k_minh_t(const float* __restrict__ in, float* __restrict__ out) {
    int i = blockIdx.x * blockDim.x + threadIdx.x;
    int y = i >> 11, xx = i & (WW - 1);
    int x0 = max(xx - RMIN, 0), x1 = min(xx + RMIN, WW - 1);
    const float* row = in + y * WW;
    float m = 1e30f;
    for (int j = x0; j <= x1; ++j) m = fminf(m, row[j]);
    out[i] = 1.0f - OMEGA * m;
}

// ---------- dark-channel max ----------
__global__ void k_dcmax(const float* __restrict__ dc, UdcpState* st) {
    __shared__ float red[256];
    float m = 0.f;
    for (int i = blockIdx.x * blockDim.x + threadIdx.x; i < HWSZ;
         i += gridDim.x * blockDim.x)
        m = fmaxf(m, dc[i]);
    red[threadIdx.x] = m;
    __syncthreads();
    for (int s = 128; s > 0; s >>= 1) {
        if (threadIdx.x < s)
            red[threadIdx.x] = fmaxf(red[threadIdx.x], red[threadIdx.x + s]);
        __syncthreads();
    }
    if (threadIdx.x == 0) atomicMax(&st->dcmax_bits, __float_as_int(red[0]));
}

// ---------- histogram ----------
__global__ void k_hist(const float* __restrict__ dc, UdcpState* st) {
    __shared__ int h[NBINS];
    for (int j = threadIdx.x; j < NBINS; j += blockDim.x) h[j] = 0;
    __syncthreads();
    float dmax = __int_as_float(st->dcmax_bits);
    float scale = dmax > 0.f ? (float)NBINS / dmax : 0.f;
    for (int i = blockIdx.x * blockDim.x + threadIdx.x; i < HWSZ;
         i += gridDim.x * blockDim.x) {
        int b = (int)(dc[i] * scale);
        if (b > NBINS - 1) b = NBINS - 1;
        atomicAdd(&h[b], 1);
    }
    __syncthreads();
    for (int j = threadIdx.x; j < NBINS; j += blockDim.x) {
        int v = h[j];
        if (v) atomicAdd(&st->hist[j], v);
    }
}

// ---------- k-th largest bin lower edge ----------
__global__ void k_tau(UdcpState* st) {
    __shared__ int csum[256];
    int tid = threadIdx.x;
    int hi = NBINS - 1 - 32 * tid;
    int local = 0;
    for (int k = 0; k < 32; ++k) local += st->hist[hi - k];
    csum[tid] = local;
    __syncthreads();
    if (tid == 0) {
        float dmax = __int_as_float(st->dcmax_bits);
        int cum = 0;
        float tau = 0.f;
        bool done = false;
        for (int c = 0; c < 256 && !done; ++c) {
            if (cum + csum[c] >= KTOP) {
                int h2 = NBINS - 1 - 32 * c;
                int cc = cum;
                for (int k = 0; k < 32; ++k) {
                    cc += st->hist[h2 - k];
                    if (cc >= KTOP) {
                        tau = (float)(h2 - k) * dmax / (float)NBINS;
                        done = true;
                        break;
                    }
                }
            } else {
                cum += csum[c];
            }
        }
        st->tau = tau;
    }
}

// ---------- atmospheric light ----------
__global__ void k_A(const float* __restrict__ dc, const float* __restrict__ x,
                    UdcpState* st) {
    int i = blockIdx.x * blockDim.x + threadIdx.x;
    float tau = st->tau;
    if (dc[i] >= tau) {
        atomicMax(&st->A_bits[0], __float_as_int(x[i]));
        atomicMax(&st->A_bits[1], __float_as_int(x[HWSZ + i]));
        atomicMax(&st->A_bits[2], __float_as_int(x[2 * HWSZ + i]));
    }
}

// ---------- normalized min(G/A1, B/A2) ----------
__global__ void k_s(const float* __restrict__ x, const UdcpState* st,
                    float* __restrict__ s) {
    int i = blockIdx.x * blockDim.x + threadIdx.x;
    float A1 = __int_as_float(st->A_bits[1]);
    float A2 = __int_as_float(st->A_bits[2]);
    s[i] = fminf(x[HWSZ + i] / A1, x[2 * HWSZ + i] / A2);
}

// ---------- horizontal 121-box on 4 fields via LDS prefix sum ----------
__global__ __launch_bounds__(256) void k_boxh4_ps(
        const float* __restrict__ g, const float* __restrict__ t,
        float* __restrict__ hg, float* __restrict__ ht,
        float* __restrict__ hgt, float* __restrict__ hgg) {
    __shared__ float P0[WW], P1[WW], P2[WW], P3[WW];
    __shared__ float wtot[4][4];
    int tid = threadIdx.x;
    int base = blockIdx.x * WW + tid * 8;
    const float4* gp = (const float4*)(g + base);
    const float4* tp = (const float4*)(t + base);
    float4 ga = gp[0], gb = gp[1];
    float4 ta = tp[0], tb = tp[1];
    float gv[8] = {ga.x, ga.y, ga.z, ga.w, gb.x, gb.y, gb.z, gb.w};
    float tv[8] = {ta.x, ta.y, ta.z, ta.w, tb.x, tb.y, tb.z, tb.w};
    float e0[8], e1[8], e2[8], e3[8];
    float s0 = 0.f, s1 = 0.f, s2 = 0.f, s3 = 0.f;
#pragma unroll
    for (int j = 0; j < 8; ++j) {
        s0 += gv[j]; e0[j] = s0;
        s1 += tv[j]; e1[j] = s1;
        s2 += gv[j] * tv[j]; e2[j] = s2;
        s3 += gv[j] * gv[j]; e3[j] = s3;
    }
    int lane = tid & 63, wv = tid >> 6;
    float i0 = s0, i1 = s1, i2 = s2, i3 = s3;
#pragma unroll
    for (int d = 1; d < 64; d <<= 1) {
        float u0 = __shfl_up(i0, d), u1 = __shfl_up(i1, d);
        float u2 = __shfl_up(i2, d), u3 = __shfl_up(i3, d);
        if (lane >= d) { i0 += u0; i1 += u1; i2 += u2; i3 += u3; }
    }
    if (lane == 63) {
        wtot[wv][0] = i0; wtot[wv][1] = i1; wtot[wv][2] = i2; wtot[wv][3] = i3;
    }
    __syncthreads();
    float off0 = i0 - s0, off1 = i1 - s1, off2 = i2 - s2, off3 = i3 - s3;
    for (int w = 0; w < wv; ++w) {
        off0 += wtot[w][0]; off1 += wtot[w][1];
        off2 += wtot[w][2]; off3 += wtot[w][3];
    }
    int xb = tid * 8;
#pragma unroll
    for (int j = 0; j < 8; ++j) {
        P0[xb + j] = e0[j] + off0;
        P1[xb + j] = e1[j] + off1;
        P2[xb + j] = e2[j] + off2;
        P3[xb + j] = e3[j] + off3;
    }
    __syncthreads();
    float o0[8], o1[8], o2[8], o3[8];
#pragma unroll
    for (int j = 0; j < 8; ++j) {
        int xx = xb + j;
        int hi = min(xx + RBOX, WW - 1);
        int lo = xx - RBOX - 1;
        float a0 = P0[hi], a1 = P1[hi], a2 = P2[hi], a3 = P3[hi];
        float b0 = 0.f, b1 = 0.f, b2 = 0.f, b3 = 0.f;
        if (lo >= 0) { b0 = P0[lo]; b1 = P1[lo]; b2 = P2[lo]; b3 = P3[lo]; }
        o0[j] = a0 - b0; o1[j] = a1 - b1; o2[j] = a2 - b2; o3[j] = a3 - b3;
    }
    ((float4*)(hg + base))[0] = make_float4(o0[0], o0[1], o0[2], o0[3]);
    ((float4*)(hg + base))[1] = make_float4(o0[4], o0[5], o0[6], o0[7]);
    ((float4*)(ht + base))[0] = make_float4(o1[0], o1[1], o1[2], o1[3]);
    ((float4*)(ht + base))[1] = make_float4(o1[4], o1[5], o1[6], o1[7]);
    ((float4*)(hgt + base))[0] = make_float4(o2[0], o2[1], o2[2], o2[3]);
    ((float4*)(hgt + base))[1] = make_float4(o2[4], o2[5], o2[6], o2[7]);
    ((float4*)(hgg + base))[0] = make_float4(o3[0], o3[1], o3[2], o3[3]);
    ((float4*)(hgg + base))[1] = make_float4(o3[4], o3[5], o3[6], o3[7]);
}

// ---------- horizontal 121-box on 2 fields via LDS prefix sum ----------
__global__ __launch_bounds__(256) void k_boxh2_ps(
        const float* __restrict__ a, const float* __restrict__ b,
        float* __restrict__ ha, float* __restrict__ hb) {
    __shared__ float P0[WW], P1[WW];
    __shared__ float wtot[4][2];
    int tid = threadIdx.x;
    int base = blockIdx.x * WW + tid * 8;
    const float4* ap = (const float4*)(a + base);
    const float4* bp = (const float4*)(b + base);
    float4 aa = ap[0], ab = ap[1];
    float4 ba = bp[0], bb = bp[1];
    float av[8] = {aa.x, aa.y, aa.z, aa.w, ab.x, ab.y, ab.z, ab.w};
    float bv[8] = {ba.x, ba.y, ba.z, ba.w, bb.x, bb.y, bb.z, bb.w};
    float e0[8], e1[8];
    float s0 = 0.f, s1 = 0.f;
#pragma unroll
    for (int j = 0; j < 8; ++j) {
        s0 += av[j]; e0[j] = s0;
        s1 += bv[j]; e1[j] = s1;
    }
    int lane = tid & 63, wv = tid >> 6;
    float i0 = s0, i1 = s1;
#pragma unroll
    for (int d = 1; d < 64; d <<= 1) {
        float u0 = __shfl_up(i0, d), u1 = __shfl_up(i1, d);
        if (lane >= d) { i0 += u0; i1 += u1; }
    }
    if (lane == 63) { wtot[wv][0] = i0; wtot[wv][1] = i1; }
    __syncthreads();
    float off0 = i0 - s0, off1 = i1 - s1;
    for (int w = 0; w < wv; ++w) { off0 += wtot[w][0]; off1 += wtot[w][1]; }
    int xb = tid * 8;
#pragma unroll
    for (int j = 0; j < 8; ++j) {
        P0[xb + j] = e0[j] + off0;
        P1[xb + j] = e1[j] + off1;
    }
    __syncthreads();
    float o0[8], o1[8];
#pragma unroll
    for (int j = 0; j < 8; ++j) {
        int xx = xb + j;
        int hi = min(xx + RBOX, WW - 1);
        int lo = xx - RBOX - 1;
        float b0 = 0.f, b1 = 0.f;
        if (lo >= 0) { b0 = P0[lo]; b1 = P1[lo]; }
        o0[j] = P0[hi] - b0; o1[j] = P1[hi] - b1;
    }
    ((float4*)(ha + base))[0] = make_float4(o0[0], o0[1], o0[2], o0[3]);
    ((float4*)(ha + base))[1] = make_float4(o0[4], o0[5], o0[6], o0[7]);
    ((float4*)(hb + base))[0] = make_float4(o1[0], o1[1], o1[2], o1[3]);
    ((float4*)(hb + base))[1] = make_float4(o1[4], o1[5], o1[6], o1[7]);
}

// ---------- vertical running-sum 121-box on 4 fields + a/b pointwise ----------
__global__ __launch_bounds__(256) void k_boxv4ab_rs(
        const float* __restrict__ hg, const float* __restrict__ ht,
        const float* __restrict__ hgt, const float* __restrict__ hgg,
        float* __restrict__ a, float* __restrict__ b) {
    int xx = blockIdx.x * 256 + threadIdx.x;
    int y0 = blockIdx.y * SEG;
    float s0 = 0.f, s1 = 0.f, s2 = 0.f, s3 = 0.f;
    int lo = max(y0 - RBOX, 0), hi = min(y0 + RBOX, HH - 1);
    for (int yy = lo; yy <= hi; ++yy) {
        int j = yy * WW + xx;
        s0 += hg[j]; s1 += ht[j]; s2 += hgt[j]; s3 += hgg[j];
    }
    float cx = (float)(min(xx + RBOX, WW - 1) - max(xx - RBOX, 0) + 1);
    for (int y = y0; y < y0 + SEG; ++y) {
        float cy = (float)(min(y + RBOX, HH - 1) - max(y - RBOX, 0) + 1);
        float inv = 1.0f / (cy * cx);
        float mI = s0 * inv, mp = s1 * inv;
        float cov = s2 * inv - mI * mp;
        float var = s3 * inv - mI * mI;
        float av = cov / (var + GFEPS);
        int i = y * WW + xx;
        a[i] = av;
        b[i] = mp - av * mI;
        int add = y + 1 + RBOX, sub = y - RBOX;
        if (add <= HH - 1) {
            int j = add * WW + xx;
            s0 += hg[j]; s1 += ht[j]; s2 += hgt[j]; s3 += hgg[j];
        }
        if (sub >= 0) {
            int j = sub * WW + xx;
            s0 -= hg[j]; s1 -= ht[j]; s2 -= hgt[j]; s3 -= hgg[j];
        }
    }
}

// ---------- vertical running-sum 121-box on (a,b) + radiance recovery ----------
__global__ __launch_bounds__(256) void k_final_rs(
        const float* __restrict__ ha, const float* __restrict__ hb,
        const float* __restrict__ g, const float* __restrict__ x,
        const UdcpState* st, float* __restrict__ out) {
    int xx = blockIdx.x * 256 + threadIdx.x;
    int y0 = blockIdx.y * SEG;
    float A0 = __int_as_float(st->A_bits[0]);
    float A1 = __int_as_float(st->A_bits[1]);
    float A2 = __int_as_float(st->A_bits[2]);
    float s0 = 0.f, s1 = 0.f;
    int lo = max(y0 - RBOX, 0), hi = min(y0 + RBOX, HH - 1);
    for (int yy = lo; yy <= hi; ++yy) {
        int j = yy * WW + xx;
        s0 += ha[j]; s1 += hb[j];
    }
    float cx = (float)(min(xx + RBOX, WW - 1) - max(xx - RBOX, 0) + 1);
    for (int y = y0; y < y0 + SEG; ++y) {
        float cy = (float)(min(y + RBOX, HH - 1) - max(y - RBOX, 0) + 1);
        float inv = 1.0f / (cy * cx);
        int i = y * WW + xx;
        float q = s0 * inv * g[i] + s1 * inv;
        float invt = 1.0f / fmaxf(q, T0C);
        float J0 = (x[i] - A0) * invt + A0;
        float J1 = (x[HWSZ + i] - A1) * invt + A1;
        float J2 = (x[2 * HWSZ + i] - A2) * invt + A2;
        out[i] = fminf(fmaxf(J0, 0.f), 1.f);
        out[HWSZ + i] = fminf(fmaxf(J1, 0.f), 1.f);
        out[2 * HWSZ + i] = fminf(fmaxf(J2, 0.f), 1.f);
        int add = y + 1 + RBOX, sub = y - RBOX;
        if (add <= HH - 1) {
            int j = add * WW + xx;
            s0 += ha[j]; s1 += hb[j];
        }
        if (sub >= 0) {
            int j = sub * WW + xx;
            s0 -= ha[j]; s1 -= hb[j];
        }
    }
}

extern "C" void kernel_launch(void* const* d_in, const int* in_sizes, int n_in,
                              void* d_out, int out_size, void* d_ws, size_t ws_size,
                              hipStream_t stream) {
    const float* x = (const float*)d_in[0];
    float* out = (float*)d_out;
    char* ws = (char*)d_ws;
    UdcpState* st = (UdcpState*)ws;
    float* B0 = (float*)(ws + 65536);
    float* B1 = B0 + HWSZ;
    float* B2 = B1 + HWSZ;
    float* B3 = B2 + HWSZ;
    float* B4 = B3 + HWSZ;
    float* B5 = B4 + HWSZ;
    float* B6 = B5 + HWSZ;

    hipMemsetAsync(st, 0, sizeof(UdcpState), stream);

    const int NB = HWSZ / 256;
    dim3 blk(256);
    dim3 vgrid(WW / 256, HH / SEG);

    // dark channel
    k_prep<<<NB, blk, 0, stream>>>(x, B0, B3);       // B0 = min(G,B), B3 = guide
    k_minv<<<NB, blk, 0, stream>>>(B0, B1);
    k_minh<<<NB, blk, 0, stream>>>(B1, B2);          // B2 = dc

    // atmospheric light
    k_dcmax<<<2048, blk, 0, stream>>>(B2, st);
    k_hist<<<256, blk, 0, stream>>>(B2, st);
    k_tau<<<1, blk, 0, stream>>>(st);
    k_A<<<NB, blk, 0, stream>>>(B2, x, st);

    // transmission
    k_s<<<NB, blk, 0, stream>>>(x, st, B0);          // B0 = min(G/A1, B/A2)
    k_minv<<<NB, blk, 0, stream>>>(B0, B1);
    k_minh_t<<<NB, blk, 0, stream>>>(B1, B0);        // B0 = t

    // guided filter
    k_boxh4_ps<<<HH, blk, 0, stream>>>(B3, B0, B1, B2, B4, B5);
    k_boxv4ab_rs<<<vgrid, blk, 0, stream>>>(B1, B2, B4, B5, B6, B0);  // B6=a, B0=b
    k_boxh2_ps<<<HH, blk, 0, stream>>>(B6, B0, B1, B2);
    k_final_rs<<<vgrid, blk, 0, stream>>>(B1, B2, B3, x, st, out);
}

// Round 3
// 332.655 us; speedup vs baseline: 3.0629x; 1.5668x over previous
//
#include <hip/hip_runtime.h>
#include <math.h>

#define HH 2048
#define WW 2048
#define HWSZ (HH*WW)
#define RMIN 7
#define RBOX 60
#define NBINS 8192
#define KTOP 4194
#define OMEGA 0.95f
#define T0C 0.1f
#define GFEPS 1e-4f
#define SEGV 16

struct UdcpState {
    int hist[NBINS];
    float tau;
    int A_bits[3];
};

// ---------- vertical 15-min of min(G,B), 8 outputs/thread ----------
__global__ __launch_bounds__(256) void k_minv8_gb(const float* __restrict__ x,
                                                  float* __restrict__ out) {
    int xx = blockIdx.x * 256 + threadIdx.x;
    int y0 = blockIdx.y * 8;
    float r[22];
#pragma unroll
    for (int j = 0; j < 22; ++j) {
        int y = y0 + j - 7;
        if (y >= 0 && y < HH) {
            int i = y * WW + xx;
            r[j] = fminf(x[HWSZ + i], x[2 * HWSZ + i]);
        } else {
            r[j] = 1e30f;
        }
    }
    float suf[15];
    suf[14] = r[14];
#pragma unroll
    for (int j = 13; j >= 0; --j) suf[j] = fminf(r[j], suf[j + 1]);
    float pre = 1e30f;
#pragma unroll
    for (int j = 0; j < 8; ++j) {
        out[(y0 + j) * WW + xx] = fminf(suf[j], pre);
        if (j < 7) pre = fminf(pre, r[15 + j]);
    }
}

// ---------- vertical 15-min of min(G/A1,B/A2), 8 outputs/thread ----------
__global__ __launch_bounds__(256) void k_minv8_s(const float* __restrict__ x,
                                                 const UdcpState* __restrict__ st,
                                                 float* __restrict__ out) {
    int xx = blockIdx.x * 256 + threadIdx.x;
    int y0 = blockIdx.y * 8;
    float iA1 = 1.0f / __int_as_float(st->A_bits[1]);
    float iA2 = 1.0f / __int_as_float(st->A_bits[2]);
    float r[22];
#pragma unroll
    for (int j = 0; j < 22; ++j) {
        int y = y0 + j - 7;
        if (y >= 0 && y < HH) {
            int i = y * WW + xx;
            r[j] = fminf(x[HWSZ + i] * iA1, x[2 * HWSZ + i] * iA2);
        } else {
            r[j] = 1e30f;
        }
    }
    float suf[15];
    suf[14] = r[14];
#pragma unroll
    for (int j = 13; j >= 0; --j) suf[j] = fminf(r[j], suf[j + 1]);
    float pre = 1e30f;
#pragma unroll
    for (int j = 0; j < 8; ++j) {
        out[(y0 + j) * WW + xx] = fminf(suf[j], pre);
        if (j < 7) pre = fminf(pre, r[15 + j]);
    }
}

// ---------- horizontal 15-min -> dc, fused fixed-range histogram ----------
__global__ __launch_bounds__(256) void k_minh8_dc(const float* __restrict__ in,
                                                  float* __restrict__ dc,
                                                  UdcpState* st) {
    __shared__ int h[NBINS];
    for (int j = threadIdx.x; j < NBINS; j += 256) h[j] = 0;
    __syncthreads();
    int row = blockIdx.x;
    int xb = threadIdx.x * 8;
    const float* rp = in + row * WW;
    float r[22];
#pragma unroll
    for (int j = 0; j < 22; ++j) {
        int xc = xb + j - 7;
        r[j] = (xc >= 0 && xc < WW) ? rp[xc] : 1e30f;
    }
    float suf[15];
    suf[14] = r[14];
#pragma unroll
    for (int j = 13; j >= 0; --j) suf[j] = fminf(r[j], suf[j + 1]);
    float pre = 1e30f;
    float o[8];
#pragma unroll
    for (int j = 0; j < 8; ++j) {
        o[j] = fminf(suf[j], pre);
        if (j < 7) pre = fminf(pre, r[15 + j]);
    }
    float* dr = dc + row * WW + xb;
#pragma unroll
    for (int j = 0; j < 8; ++j) dr[j] = o[j];
#pragma unroll
    for (int j = 0; j < 8; ++j) {
        int b = (int)(o[j] * (float)NBINS);
        b = min(max(b, 0), NBINS - 1);
        atomicAdd(&h[b], 1);
    }
    __syncthreads();
    for (int j = threadIdx.x; j < NBINS; j += 256) {
        int v = h[j];
        if (v) atomicAdd(&st->hist[j], v);
    }
}

// ---------- horizontal 15-min -> t = 1 - omega*min ----------
__global__ __launch_bounds__(256) void k_minh8_t(const float* __restrict__ in,
                                                 float* __restrict__ out) {
    int row = blockIdx.x;
    int xb = threadIdx.x * 8;
    const float* rp = in + row * WW;
    float r[22];
#pragma unroll
    for (int j = 0; j < 22; ++j) {
        int xc = xb + j - 7;
        r[j] = (xc >= 0 && xc < WW) ? rp[xc] : 1e30f;
    }
    float suf[15];
    suf[14] = r[14];
#pragma unroll
    for (int j = 13; j >= 0; --j) suf[j] = fminf(r[j], suf[j + 1]);
    float pre = 1e30f;
    float* orow = out + row * WW + xb;
#pragma unroll
    for (int j = 0; j < 8; ++j) {
        orow[j] = 1.0f - OMEGA * fminf(suf[j], pre);
        if (j < 7) pre = fminf(pre, r[15 + j]);
    }
}

// ---------- k-th largest bin lower edge (fixed [0,1] range) ----------
__global__ void k_tau(UdcpState* st) {
    __shared__ int csum[256];
    int tid = threadIdx.x;
    int hi = NBINS - 1 - 32 * tid;
    int local = 0;
    for (int k = 0; k < 32; ++k) local += st->hist[hi - k];
    csum[tid] = local;
    __syncthreads();
    if (tid == 0) {
        int cum = 0;
        float tau = 0.f;
        bool done = false;
        for (int c = 0; c < 256 && !done; ++c) {
            if (cum + csum[c] >= KTOP) {
                int h2 = NBINS - 1 - 32 * c;
                int cc = cum;
                for (int k = 0; k < 32; ++k) {
                    cc += st->hist[h2 - k];
                    if (cc >= KTOP) {
                        tau = (float)(h2 - k) / (float)NBINS;
                        done = true;
                        break;
                    }
                }
            } else {
                cum += csum[c];
            }
        }
        st->tau = tau;
    }
}

// ---------- atmospheric light ----------
__global__ void k_A(const float* __restrict__ dc, const float* __restrict__ x,
                    UdcpState* st) {
    int i = blockIdx.x * blockDim.x + threadIdx.x;
    float tau = st->tau;
    if (dc[i] >= tau) {
        atomicMax(&st->A_bits[0], __float_as_int(x[i]));
        atomicMax(&st->A_bits[1], __float_as_int(x[HWSZ + i]));
        atomicMax(&st->A_bits[2], __float_as_int(x[2 * HWSZ + i]));
    }
}

// ---------- horizontal 121-box on 4 fields via LDS prefix sum, guide inline ----------
__global__ __launch_bounds__(256) void k_boxh4_ps(
        const float* __restrict__ x, const float* __restrict__ t,
        float4* __restrict__ f4) {
    __shared__ float P0[WW], P1[WW], P2[WW], P3[WW];
    __shared__ float wtot[4][4];
    int tid = threadIdx.x;
    int base = blockIdx.x * WW + tid * 8;
    float4 Ra = *(const float4*)(x + base), Rb = *(const float4*)(x + base + 4);
    float4 Ga = *(const float4*)(x + HWSZ + base), Gb = *(const float4*)(x + HWSZ + base + 4);
    float4 Ba = *(const float4*)(x + 2 * HWSZ + base), Bb = *(const float4*)(x + 2 * HWSZ + base + 4);
    float4 ta = *(const float4*)(t + base), tb = *(const float4*)(t + base + 4);
    float Rv[8] = {Ra.x, Ra.y, Ra.z, Ra.w, Rb.x, Rb.y, Rb.z, Rb.w};
    float Gv[8] = {Ga.x, Ga.y, Ga.z, Ga.w, Gb.x, Gb.y, Gb.z, Gb.w};
    float Bv[8] = {Ba.x, Ba.y, Ba.z, Ba.w, Bb.x, Bb.y, Bb.z, Bb.w};
    float tv[8] = {ta.x, ta.y, ta.z, ta.w, tb.x, tb.y, tb.z, tb.w};
    float gv[8];
#pragma unroll
    for (int j = 0; j < 8; ++j)
        gv[j] = 0.299f * Rv[j] + 0.587f * Gv[j] + 0.114f * Bv[j];
    float e0[8], e1[8], e2[8], e3[8];
    float s0 = 0.f, s1 = 0.f, s2 = 0.f, s3 = 0.f;
#pragma unroll
    for (int j = 0; j < 8; ++j) {
        s0 += gv[j]; e0[j] = s0;
        s1 += tv[j]; e1[j] = s1;
        s2 += gv[j] * tv[j]; e2[j] = s2;
        s3 += gv[j] * gv[j]; e3[j] = s3;
    }
    int lane = tid & 63, wv = tid >> 6;
    float i0 = s0, i1 = s1, i2 = s2, i3 = s3;
#pragma unroll
    for (int d = 1; d < 64; d <<= 1) {
        float u0 = __shfl_up(i0, d), u1 = __shfl_up(i1, d);
        float u2 = __shfl_up(i2, d), u3 = __shfl_up(i3, d);
        if (lane >= d) { i0 += u0; i1 += u1; i2 += u2; i3 += u3; }
    }
    if (lane == 63) {
        wtot[wv][0] = i0; wtot[wv][1] = i1; wtot[wv][2] = i2; wtot[wv][3] = i3;
    }
    __syncthreads();
    float off0 = i0 - s0, off1 = i1 - s1, off2 = i2 - s2, off3 = i3 - s3;
    for (int w = 0; w < wv; ++w) {
        off0 += wtot[w][0]; off1 += wtot[w][1];
        off2 += wtot[w][2]; off3 += wtot[w][3];
    }
    int xb = tid * 8;
#pragma unroll
    for (int j = 0; j < 8; ++j) {
        P0[xb + j] = e0[j] + off0;
        P1[xb + j] = e1[j] + off1;
        P2[xb + j] = e2[j] + off2;
        P3[xb + j] = e3[j] + off3;
    }
    __syncthreads();
#pragma unroll
    for (int j = 0; j < 8; ++j) {
        int xx = xb + j;
        int hi = min(xx + RBOX, WW - 1);
        int lo = xx - RBOX - 1;
        float b0 = 0.f, b1 = 0.f, b2 = 0.f, b3 = 0.f;
        if (lo >= 0) { b0 = P0[lo]; b1 = P1[lo]; b2 = P2[lo]; b3 = P3[lo]; }
        f4[base + j] = make_float4(P0[hi] - b0, P1[hi] - b1, P2[hi] - b2, P3[hi] - b3);
    }
}

// ---------- vertical running-sum 121-box on float4 fields + a/b ----------
__global__ __launch_bounds__(256) void k_boxv4ab_rs(const float4* __restrict__ f4,
                                                    float2* __restrict__ ab) {
    int xx = blockIdx.x * 256 + threadIdx.x;
    int y0 = blockIdx.y * SEGV;
    float s0 = 0.f, s1 = 0.f, s2 = 0.f, s3 = 0.f;
    int lo = max(y0 - RBOX, 0), hi = min(y0 + RBOX, HH - 1);
#pragma unroll 8
    for (int yy = lo; yy <= hi; ++yy) {
        float4 v = f4[yy * WW + xx];
        s0 += v.x; s1 += v.y; s2 += v.z; s3 += v.w;
    }
    float cx = (float)(min(xx + RBOX, WW - 1) - max(xx - RBOX, 0) + 1);
#pragma unroll
    for (int y = y0; y < y0 + SEGV; ++y) {
        float cy = (float)(min(y + RBOX, HH - 1) - max(y - RBOX, 0) + 1);
        float inv = 1.0f / (cy * cx);
        float mI = s0 * inv, mp = s1 * inv;
        float cov = s2 * inv - mI * mp;
        float var = s3 * inv - mI * mI;
        float av = cov / (var + GFEPS);
        ab[y * WW + xx] = make_float2(av, mp - av * mI);
        int add = y + 1 + RBOX, sub = y - RBOX;
        if (add < HH) {
            float4 v = f4[add * WW + xx];
            s0 += v.x; s1 += v.y; s2 += v.z; s3 += v.w;
        }
        if (sub >= 0) {
            float4 v = f4[sub * WW + xx];
            s0 -= v.x; s1 -= v.y; s2 -= v.z; s3 -= v.w;
        }
    }
}

// ---------- horizontal 121-box on (a,b) float2 via LDS prefix sum ----------
__global__ __launch_bounds__(256) void k_boxh2_ps(const float2* __restrict__ ab,
                                                  float2* __restrict__ hab) {
    __shared__ float P0[WW], P1[WW];
    __shared__ float wtot[4][2];
    int tid = threadIdx.x;
    int base = blockIdx.x * WW + tid * 8;
    const float4* ap = (const float4*)(ab + base);
    float4 q0 = ap[0], q1 = ap[1], q2 = ap[2], q3 = ap[3];
    float av[8] = {q0.x, q0.z, q1.x, q1.z, q2.x, q2.z, q3.x, q3.z};
    float bv[8] = {q0.y, q0.w, q1.y, q1.w, q2.y, q2.w, q3.y, q3.w};
    float e0[8], e1[8];
    float s0 = 0.f, s1 = 0.f;
#pragma unroll
    for (int j = 0; j < 8; ++j) {
        s0 += av[j]; e0[j] = s0;
        s1 += bv[j]; e1[j] = s1;
    }
    int lane = tid & 63, wv = tid >> 6;
    float i0 = s0, i1 = s1;
#pragma unroll
    for (int d = 1; d < 64; d <<= 1) {
        float u0 = __shfl_up(i0, d), u1 = __shfl_up(i1, d);
        if (lane >= d) { i0 += u0; i1 += u1; }
    }
    if (lane == 63) { wtot[wv][0] = i0; wtot[wv][1] = i1; }
    __syncthreads();
    float off0 = i0 - s0, off1 = i1 - s1;
    for (int w = 0; w < wv; ++w) { off0 += wtot[w][0]; off1 += wtot[w][1]; }
    int xb = tid * 8;
#pragma unroll
    for (int j = 0; j < 8; ++j) {
        P0[xb + j] = e0[j] + off0;
        P1[xb + j] = e1[j] + off1;
    }
    __syncthreads();
#pragma unroll
    for (int j = 0; j < 8; ++j) {
        int xx = xb + j;
        int hi = min(xx + RBOX, WW - 1);
        int lo = xx - RBOX - 1;
        float b0 = 0.f, b1 = 0.f;
        if (lo >= 0) { b0 = P0[lo]; b1 = P1[lo]; }
        hab[base + j] = make_float2(P0[hi] - b0, P1[hi] - b1);
    }
}

// ---------- vertical running-sum 121-box on (a,b) + recovery ----------
__global__ __launch_bounds__(256) void k_final_rs(const float2* __restrict__ hab,
                                                  const float* __restrict__ x,
                                                  const UdcpState* __restrict__ st,
                                                  float* __restrict__ out) {
    int xx = blockIdx.x * 256 + threadIdx.x;
    int y0 = blockIdx.y * SEGV;
    float A0 = __int_as_float(st->A_bits[0]);
    float A1 = __int_as_float(st->A_bits[1]);
    float A2 = __int_as_float(st->A_bits[2]);
    float s0 = 0.f, s1 = 0.f;
    int lo = max(y0 - RBOX, 0), hi = min(y0 + RBOX, HH - 1);
#pragma unroll 8
    for (int yy = lo; yy <= hi; ++yy) {
        float2 v = hab[yy * WW + xx];
        s0 += v.x; s1 += v.y;
    }
    float cx = (float)(min(xx + RBOX, WW - 1) - max(xx - RBOX, 0) + 1);
#pragma unroll
    for (int y = y0; y < y0 + SEGV; ++y) {
        float cy = (float)(min(y + RBOX, HH - 1) - max(y - RBOX, 0) + 1);
        float inv = 1.0f / (cy * cx);
        int i = y * WW + xx;
        float R = x[i], G = x[HWSZ + i], B = x[2 * HWSZ + i];
        float guide = 0.299f * R + 0.587f * G + 0.114f * B;
        float q = s0 * inv * guide + s1 * inv;
        float invt = 1.0f / fmaxf(q, T0C);
        float J0 = (R - A0) * invt + A0;
        float J1 = (G - A1) * invt + A1;
        float J2 = (B - A2) * invt + A2;
        out[i] = fminf(fmaxf(J0, 0.f), 1.f);
        out[HWSZ + i] = fminf(fmaxf(J1, 0.f), 1.f);
        out[2 * HWSZ + i] = fminf(fmaxf(J2, 0.f), 1.f);
        int add = y + 1 + RBOX, sub = y - RBOX;
        if (add < HH) {
            float2 v = hab[add * WW + xx];
            s0 += v.x; s1 += v.y;
        }
        if (sub >= 0) {
            float2 v = hab[sub * WW + xx];
            s0 -= v.x; s1 -= v.y;
        }
    }
}

extern "C" void kernel_launch(void* const* d_in, const int* in_sizes, int n_in,
                              void* d_out, int out_size, void* d_ws, size_t ws_size,
                              hipStream_t stream) {
    const float* x = (const float*)d_in[0];
    float* out = (float*)d_out;
    char* ws = (char*)d_ws;
    UdcpState* st = (UdcpState*)ws;
    float* M0 = (float*)(ws + 65536);
    float* M1 = M0 + HWSZ;
    float* M2 = M1 + HWSZ;
    float4* F4 = (float4*)(M2 + HWSZ);
    float2* AB = (float2*)M0;       // spans M0+M1 after dc/tmp are dead
    float2* HAB = (float2*)F4;      // reuses F4 after it is consumed

    hipMemsetAsync(st, 0, sizeof(UdcpState), stream);

    dim3 blk(256);
    dim3 mgrid(WW / 256, HH / 8);
    dim3 vgrid(WW / 256, HH / SEGV);

    // dark channel + histogram
    k_minv8_gb<<<mgrid, blk, 0, stream>>>(x, M1);
    k_minh8_dc<<<HH, blk, 0, stream>>>(M1, M0, st);   // M0 = dc
    k_tau<<<1, blk, 0, stream>>>(st);
    k_A<<<HWSZ / 256, blk, 0, stream>>>(M0, x, st);

    // transmission
    k_minv8_s<<<mgrid, blk, 0, stream>>>(x, st, M1);
    k_minh8_t<<<HH, blk, 0, stream>>>(M1, M2);        // M2 = t

    // guided filter
    k_boxh4_ps<<<HH, blk, 0, stream>>>(x, M2, F4);
    k_boxv4ab_rs<<<vgrid, blk, 0, stream>>>(F4, AB);
    k_boxh2_ps<<<HH, blk, 0, stream>>>(AB, HAB);
    k_final_rs<<<vgrid, blk, 0, stream>>>(HAB, x, st, out);
}

// Round 4
// 298.946 us; speedup vs baseline: 3.4083x; 1.1128x over previous
//
#include <hip/hip_runtime.h>
#include <math.h>

#define HH 2048
#define WW 2048
#define HWSZ (HH*WW)
#define RMIN 7
#define RBOX 60
#define NBINS 8192
#define KTOP 4194
#define OMEGA 0.95f
#define T0C 0.1f
#define GFEPS 1e-4f
#define SEGV 32

struct UdcpState {
    int hist[NBINS];
    float tau;
    int A_bits[3];
};

// ---------- vertical 15-min of min(G,B), 8 outputs/thread ----------
__global__ __launch_bounds__(256) void k_minv8_gb(const float* __restrict__ x,
                                                  float* __restrict__ out) {
    int xx = blockIdx.x * 256 + threadIdx.x;
    int y0 = blockIdx.y * 8;
    float r[22];
#pragma unroll
    for (int j = 0; j < 22; ++j) {
        int y = y0 + j - 7;
        if (y >= 0 && y < HH) {
            int i = y * WW + xx;
            r[j] = fminf(x[HWSZ + i], x[2 * HWSZ + i]);
        } else {
            r[j] = 1e30f;
        }
    }
    float suf[15];
    suf[14] = r[14];
#pragma unroll
    for (int j = 13; j >= 0; --j) suf[j] = fminf(r[j], suf[j + 1]);
    float pre = 1e30f;
#pragma unroll
    for (int j = 0; j < 8; ++j) {
        out[(y0 + j) * WW + xx] = fminf(suf[j], pre);
        if (j < 7) pre = fminf(pre, r[15 + j]);
    }
}

// ---------- vertical 15-min of min(G/A1,B/A2), 8 outputs/thread ----------
__global__ __launch_bounds__(256) void k_minv8_s(const float* __restrict__ x,
                                                 const UdcpState* __restrict__ st,
                                                 float* __restrict__ out) {
    int xx = blockIdx.x * 256 + threadIdx.x;
    int y0 = blockIdx.y * 8;
    float iA1 = 1.0f / __int_as_float(st->A_bits[1]);
    float iA2 = 1.0f / __int_as_float(st->A_bits[2]);
    float r[22];
#pragma unroll
    for (int j = 0; j < 22; ++j) {
        int y = y0 + j - 7;
        if (y >= 0 && y < HH) {
            int i = y * WW + xx;
            r[j] = fminf(x[HWSZ + i] * iA1, x[2 * HWSZ + i] * iA2);
        } else {
            r[j] = 1e30f;
        }
    }
    float suf[15];
    suf[14] = r[14];
#pragma unroll
    for (int j = 13; j >= 0; --j) suf[j] = fminf(r[j], suf[j + 1]);
    float pre = 1e30f;
#pragma unroll
    for (int j = 0; j < 8; ++j) {
        out[(y0 + j) * WW + xx] = fminf(suf[j], pre);
        if (j < 7) pre = fminf(pre, r[15 + j]);
    }
}

// ---------- horizontal 15-min -> dc, fused fixed-range histogram ----------
__global__ __launch_bounds__(256) void k_minh8_dc(const float* __restrict__ in,
                                                  float* __restrict__ dc,
                                                  UdcpState* st) {
    __shared__ int h[NBINS];
    for (int j = threadIdx.x; j < NBINS; j += 256) h[j] = 0;
    __syncthreads();
    int row = blockIdx.x;
    int xb = threadIdx.x * 8;
    const float* rp = in + row * WW;
    float r[22];
#pragma unroll
    for (int j = 0; j < 22; ++j) {
        int xc = xb + j - 7;
        r[j] = (xc >= 0 && xc < WW) ? rp[xc] : 1e30f;
    }
    float suf[15];
    suf[14] = r[14];
#pragma unroll
    for (int j = 13; j >= 0; --j) suf[j] = fminf(r[j], suf[j + 1]);
    float pre = 1e30f;
    float o[8];
#pragma unroll
    for (int j = 0; j < 8; ++j) {
        o[j] = fminf(suf[j], pre);
        if (j < 7) pre = fminf(pre, r[15 + j]);
    }
    float* dr = dc + row * WW + xb;
#pragma unroll
    for (int j = 0; j < 8; ++j) dr[j] = o[j];
#pragma unroll
    for (int j = 0; j < 8; ++j) {
        int b = (int)(o[j] * (float)NBINS);
        b = min(max(b, 0), NBINS - 1);
        atomicAdd(&h[b], 1);
    }
    __syncthreads();
    for (int j = threadIdx.x; j < NBINS; j += 256) {
        int v = h[j];
        if (v) atomicAdd(&st->hist[j], v);
    }
}

// ---------- k-th largest bin lower edge (fixed [0,1] range) ----------
__global__ void k_tau(UdcpState* st) {
    __shared__ int csum[256];
    int tid = threadIdx.x;
    int hi = NBINS - 1 - 32 * tid;
    int local = 0;
    for (int k = 0; k < 32; ++k) local += st->hist[hi - k];
    csum[tid] = local;
    __syncthreads();
    if (tid == 0) {
        int cum = 0;
        float tau = 0.f;
        bool done = false;
        for (int c = 0; c < 256 && !done; ++c) {
            if (cum + csum[c] >= KTOP) {
                int h2 = NBINS - 1 - 32 * c;
                int cc = cum;
                for (int k = 0; k < 32; ++k) {
                    cc += st->hist[h2 - k];
                    if (cc >= KTOP) {
                        tau = (float)(h2 - k) / (float)NBINS;
                        done = true;
                        break;
                    }
                }
            } else {
                cum += csum[c];
            }
        }
        st->tau = tau;
    }
}

// ---------- atmospheric light: block-level reduce, few atomics ----------
__global__ __launch_bounds__(256) void k_A2(const float* __restrict__ dc,
                                            const float* __restrict__ x,
                                            UdcpState* st) {
    __shared__ float r0[256], r1[256], r2[256];
    __shared__ int anyflag;
    if (threadIdx.x == 0) anyflag = 0;
    __syncthreads();
    float tau = st->tau;
    const float4* dc4 = (const float4*)dc;
    int base4 = blockIdx.x * 1024;
    float m0 = -1e30f, m1 = -1e30f, m2 = -1e30f;
    bool found = false;
#pragma unroll
    for (int k = 0; k < 4; ++k) {
        int q = base4 + k * 256 + threadIdx.x;
        float4 v = dc4[q];
        float dv[4] = {v.x, v.y, v.z, v.w};
#pragma unroll
        for (int c = 0; c < 4; ++c) {
            if (dv[c] >= tau) {
                int i = q * 4 + c;
                m0 = fmaxf(m0, x[i]);
                m1 = fmaxf(m1, x[HWSZ + i]);
                m2 = fmaxf(m2, x[2 * HWSZ + i]);
                found = true;
            }
        }
    }
    if (found) anyflag = 1;
    __syncthreads();
    if (!anyflag) return;
    r0[threadIdx.x] = m0; r1[threadIdx.x] = m1; r2[threadIdx.x] = m2;
    __syncthreads();
    for (int s = 128; s > 0; s >>= 1) {
        if (threadIdx.x < s) {
            r0[threadIdx.x] = fmaxf(r0[threadIdx.x], r0[threadIdx.x + s]);
            r1[threadIdx.x] = fmaxf(r1[threadIdx.x], r1[threadIdx.x + s]);
            r2[threadIdx.x] = fmaxf(r2[threadIdx.x], r2[threadIdx.x + s]);
        }
        __syncthreads();
    }
    if (threadIdx.x == 0 && r0[0] > -1e29f) {
        atomicMax(&st->A_bits[0], __float_as_int(r0[0]));
        atomicMax(&st->A_bits[1], __float_as_int(r1[0]));
        atomicMax(&st->A_bits[2], __float_as_int(r2[0]));
    }
}

// ---------- fused: horizontal 15-min -> t, then 121-box prefix on 4 fields ----------
__global__ __launch_bounds__(256) void k_boxh4f(
        const float* __restrict__ x, const float* __restrict__ sv,
        float4* __restrict__ f4) {
    __shared__ float P0[WW], P1[WW], P2[WW], P3[WW];
    __shared__ float mrow[WW];
    __shared__ float wtot[4][4];
    int tid = threadIdx.x;
    int base = blockIdx.x * WW + tid * 8;
    int xb = tid * 8;
    // stage vertical-s-min row
    {
        float4 ma = *(const float4*)(sv + base);
        float4 mb = *(const float4*)(sv + base + 4);
        *(float4*)(mrow + xb) = ma;
        *(float4*)(mrow + xb + 4) = mb;
    }
    float4 Ra = *(const float4*)(x + base), Rb = *(const float4*)(x + base + 4);
    float4 Ga = *(const float4*)(x + HWSZ + base), Gb = *(const float4*)(x + HWSZ + base + 4);
    float4 Ba = *(const float4*)(x + 2 * HWSZ + base), Bb = *(const float4*)(x + 2 * HWSZ + base + 4);
    float Rv[8] = {Ra.x, Ra.y, Ra.z, Ra.w, Rb.x, Rb.y, Rb.z, Rb.w};
    float Gv[8] = {Ga.x, Ga.y, Ga.z, Ga.w, Gb.x, Gb.y, Gb.z, Gb.w};
    float Bv[8] = {Ba.x, Ba.y, Ba.z, Ba.w, Bb.x, Bb.y, Bb.z, Bb.w};
    __syncthreads();
    // t = 1 - omega * horizontal 15-min of mrow (van Herk)
    float tv[8];
    {
        float r[22];
#pragma unroll
        for (int j = 0; j < 22; ++j) {
            int xc = xb + j - 7;
            r[j] = (xc >= 0 && xc < WW) ? mrow[xc] : 1e30f;
        }
        float suf[15];
        suf[14] = r[14];
#pragma unroll
        for (int j = 13; j >= 0; --j) suf[j] = fminf(r[j], suf[j + 1]);
        float pre = 1e30f;
#pragma unroll
        for (int j = 0; j < 8; ++j) {
            tv[j] = 1.0f - OMEGA * fminf(suf[j], pre);
            if (j < 7) pre = fminf(pre, r[15 + j]);
        }
    }
    float gv[8];
#pragma unroll
    for (int j = 0; j < 8; ++j)
        gv[j] = 0.299f * Rv[j] + 0.587f * Gv[j] + 0.114f * Bv[j];
    float e0[8], e1[8], e2[8], e3[8];
    float s0 = 0.f, s1 = 0.f, s2 = 0.f, s3 = 0.f;
#pragma unroll
    for (int j = 0; j < 8; ++j) {
        s0 += gv[j]; e0[j] = s0;
        s1 += tv[j]; e1[j] = s1;
        s2 += gv[j] * tv[j]; e2[j] = s2;
        s3 += gv[j] * gv[j]; e3[j] = s3;
    }
    int lane = tid & 63, wv = tid >> 6;
    float i0 = s0, i1 = s1, i2 = s2, i3 = s3;
#pragma unroll
    for (int d = 1; d < 64; d <<= 1) {
        float u0 = __shfl_up(i0, d), u1 = __shfl_up(i1, d);
        float u2 = __shfl_up(i2, d), u3 = __shfl_up(i3, d);
        if (lane >= d) { i0 += u0; i1 += u1; i2 += u2; i3 += u3; }
    }
    if (lane == 63) {
        wtot[wv][0] = i0; wtot[wv][1] = i1; wtot[wv][2] = i2; wtot[wv][3] = i3;
    }
    __syncthreads();
    float off0 = i0 - s0, off1 = i1 - s1, off2 = i2 - s2, off3 = i3 - s3;
    for (int w = 0; w < wv; ++w) {
        off0 += wtot[w][0]; off1 += wtot[w][1];
        off2 += wtot[w][2]; off3 += wtot[w][3];
    }
#pragma unroll
    for (int j = 0; j < 8; ++j) {
        P0[xb + j] = e0[j] + off0;
        P1[xb + j] = e1[j] + off1;
        P2[xb + j] = e2[j] + off2;
        P3[xb + j] = e3[j] + off3;
    }
    __syncthreads();
#pragma unroll
    for (int j = 0; j < 8; ++j) {
        int xx = xb + j;
        int hi = min(xx + RBOX, WW - 1);
        int lo = xx - RBOX - 1;
        float b0 = 0.f, b1 = 0.f, b2 = 0.f, b3 = 0.f;
        if (lo >= 0) { b0 = P0[lo]; b1 = P1[lo]; b2 = P2[lo]; b3 = P3[lo]; }
        f4[base + j] = make_float4(P0[hi] - b0, P1[hi] - b1, P2[hi] - b2, P3[hi] - b3);
    }
}

// ---------- vertical running-sum 121-box on float4 fields + a/b ----------
__global__ __launch_bounds__(256) void k_boxv4ab_rs(const float4* __restrict__ f4,
                                                    float2* __restrict__ ab) {
    int xx = blockIdx.x * 256 + threadIdx.x;
    int y0 = blockIdx.y * SEGV;
    float s0 = 0.f, s1 = 0.f, s2 = 0.f, s3 = 0.f;
    int lo = max(y0 - RBOX, 0), hi = min(y0 + RBOX, HH - 1);
#pragma unroll 8
    for (int yy = lo; yy <= hi; ++yy) {
        float4 v = f4[yy * WW + xx];
        s0 += v.x; s1 += v.y; s2 += v.z; s3 += v.w;
    }
    float cx = (float)(min(xx + RBOX, WW - 1) - max(xx - RBOX, 0) + 1);
#pragma unroll
    for (int y = y0; y < y0 + SEGV; ++y) {
        float cy = (float)(min(y + RBOX, HH - 1) - max(y - RBOX, 0) + 1);
        float inv = 1.0f / (cy * cx);
        float mI = s0 * inv, mp = s1 * inv;
        float cov = s2 * inv - mI * mp;
        float var = s3 * inv - mI * mI;
        float av = cov / (var + GFEPS);
        ab[y * WW + xx] = make_float2(av, mp - av * mI);
        int add = y + 1 + RBOX, sub = y - RBOX;
        if (add < HH) {
            float4 v = f4[add * WW + xx];
            s0 += v.x; s1 += v.y; s2 += v.z; s3 += v.w;
        }
        if (sub >= 0) {
            float4 v = f4[sub * WW + xx];
            s0 -= v.x; s1 -= v.y; s2 -= v.z; s3 -= v.w;
        }
    }
}

// ---------- horizontal 121-box on (a,b) float2 via LDS prefix sum ----------
__global__ __launch_bounds__(256) void k_boxh2_ps(const float2* __restrict__ ab,
                                                  float2* __restrict__ hab) {
    __shared__ float P0[WW], P1[WW];
    __shared__ float wtot[4][2];
    int tid = threadIdx.x;
    int base = blockIdx.x * WW + tid * 8;
    const float4* ap = (const float4*)(ab + base);
    float4 q0 = ap[0], q1 = ap[1], q2 = ap[2], q3 = ap[3];
    float av[8] = {q0.x, q0.z, q1.x, q1.z, q2.x, q2.z, q3.x, q3.z};
    float bv[8] = {q0.y, q0.w, q1.y, q1.w, q2.y, q2.w, q3.y, q3.w};
    float e0[8], e1[8];
    float s0 = 0.f, s1 = 0.f;
#pragma unroll
    for (int j = 0; j < 8; ++j) {
        s0 += av[j]; e0[j] = s0;
        s1 += bv[j]; e1[j] = s1;
    }
    int lane = tid & 63, wv = tid >> 6;
    float i0 = s0, i1 = s1;
#pragma unroll
    for (int d = 1; d < 64; d <<= 1) {
        float u0 = __shfl_up(i0, d), u1 = __shfl_up(i1, d);
        if (lane >= d) { i0 += u0; i1 += u1; }
    }
    if (lane == 63) { wtot[wv][0] = i0; wtot[wv][1] = i1; }
    __syncthreads();
    float off0 = i0 - s0, off1 = i1 - s1;
    for (int w = 0; w < wv; ++w) { off0 += wtot[w][0]; off1 += wtot[w][1]; }
    int xb = tid * 8;
#pragma unroll
    for (int j = 0; j < 8; ++j) {
        P0[xb + j] = e0[j] + off0;
        P1[xb + j] = e1[j] + off1;
    }
    __syncthreads();
#pragma unroll
    for (int j = 0; j < 8; ++j) {
        int xx = xb + j;
        int hi = min(xx + RBOX, WW - 1);
        int lo = xx - RBOX - 1;
        float b0 = 0.f, b1 = 0.f;
        if (lo >= 0) { b0 = P0[lo]; b1 = P1[lo]; }
        hab[base + j] = make_float2(P0[hi] - b0, P1[hi] - b1);
    }
}

// ---------- vertical running-sum 121-box on (a,b) + recovery ----------
__global__ __launch_bounds__(256) void k_final_rs(const float2* __restrict__ hab,
                                                  const float* __restrict__ x,
                                                  const UdcpState* __restrict__ st,
                                                  float* __restrict__ out) {
    int xx = blockIdx.x * 256 + threadIdx.x;
    int y0 = blockIdx.y * SEGV;
    float A0 = __int_as_float(st->A_bits[0]);
    float A1 = __int_as_float(st->A_bits[1]);
    float A2 = __int_as_float(st->A_bits[2]);
    float s0 = 0.f, s1 = 0.f;
    int lo = max(y0 - RBOX, 0), hi = min(y0 + RBOX, HH - 1);
#pragma unroll 8
    for (int yy = lo; yy <= hi; ++yy) {
        float2 v = hab[yy * WW + xx];
        s0 += v.x; s1 += v.y;
    }
    float cx = (float)(min(xx + RBOX, WW - 1) - max(xx - RBOX, 0) + 1);
#pragma unroll
    for (int y = y0; y < y0 + SEGV; ++y) {
        float cy = (float)(min(y + RBOX, HH - 1) - max(y - RBOX, 0) + 1);
        float inv = 1.0f / (cy * cx);
        int i = y * WW + xx;
        float R = x[i], G = x[HWSZ + i], B = x[2 * HWSZ + i];
        float guide = 0.299f * R + 0.587f * G + 0.114f * B;
        float q = s0 * inv * guide + s1 * inv;
        float invt = 1.0f / fmaxf(q, T0C);
        float J0 = (R - A0) * invt + A0;
        float J1 = (G - A1) * invt + A1;
        float J2 = (B - A2) * invt + A2;
        out[i] = fminf(fmaxf(J0, 0.f), 1.f);
        out[HWSZ + i] = fminf(fmaxf(J1, 0.f), 1.f);
        out[2 * HWSZ + i] = fminf(fmaxf(J2, 0.f), 1.f);
        int add = y + 1 + RBOX, sub = y - RBOX;
        if (add < HH) {
            float2 v = hab[add * WW + xx];
            s0 += v.x; s1 += v.y;
        }
        if (sub >= 0) {
            float2 v = hab[sub * WW + xx];
            s0 -= v.x; s1 -= v.y;
        }
    }
}

extern "C" void kernel_launch(void* const* d_in, const int* in_sizes, int n_in,
                              void* d_out, int out_size, void* d_ws, size_t ws_size,
                              hipStream_t stream) {
    const float* x = (const float*)d_in[0];
    float* out = (float*)d_out;
    char* ws = (char*)d_ws;
    UdcpState* st = (UdcpState*)ws;
    float* M0 = (float*)(ws + 65536);
    float* M1 = M0 + HWSZ;
    float4* F4 = (float4*)(M1 + HWSZ);
    float2* AB = (float2*)M0;       // spans M0+M1 once dc / s-min are dead
    float2* HAB = (float2*)F4;      // reuses F4 once consumed

    hipMemsetAsync(st, 0, sizeof(UdcpState), stream);

    dim3 blk(256);
    dim3 mgrid(WW / 256, HH / 8);
    dim3 vgrid(WW / 256, HH / SEGV);

    // dark channel + histogram + A
    k_minv8_gb<<<mgrid, blk, 0, stream>>>(x, M1);
    k_minh8_dc<<<HH, blk, 0, stream>>>(M1, M0, st);   // M0 = dc
    k_tau<<<1, blk, 0, stream>>>(st);
    k_A2<<<HWSZ / 4096, blk, 0, stream>>>(M0, x, st);

    // transmission (vertical stage only; horizontal fused into boxh4f)
    k_minv8_s<<<mgrid, blk, 0, stream>>>(x, st, M1);

    // guided filter
    k_boxh4f<<<HH, blk, 0, stream>>>(x, M1, F4);
    k_boxv4ab_rs<<<vgrid, blk, 0, stream>>>(F4, AB);
    k_boxh2_ps<<<HH, blk, 0, stream>>>(AB, HAB);
    k_final_rs<<<vgrid, blk, 0, stream>>>(HAB, x, st, out);
}

// Round 5
// 230.247 us; speedup vs baseline: 4.4252x; 1.2984x over previous
//
#include <hip/hip_runtime.h>
#include <math.h>

#define HH 2048
#define WW 2048
#define HWSZ (HH*WW)
#define RBOX 60
#define NBINS 8192
#define KTOP 4194
#define OMEGA 0.95f
#define T0C 0.1f
#define GFEPS 1e-4f
#define SEGV 32

struct UdcpState {
    int hist[NBINS];
    float tau;
    int A_bits[3];
};

// bf16 pair pack (round-to-nearest-even; truncation would bias cov -> bad a)
__device__ __forceinline__ unsigned pbf2(float lo, float hi) {
    unsigned ul = __float_as_uint(lo), uh = __float_as_uint(hi);
    ul += 0x7FFFu + ((ul >> 16) & 1u);
    uh += 0x7FFFu + ((uh >> 16) & 1u);
    return (ul >> 16) | (uh & 0xFFFF0000u);
}
__device__ __forceinline__ float ublo(unsigned u) { return __uint_as_float(u << 16); }
__device__ __forceinline__ float ubhi(unsigned u) { return __uint_as_float(u & 0xFFFF0000u); }

// ---------- vertical 15-min of G and B separately -> packed bf16 pair ----------
__global__ __launch_bounds__(256) void k_minv8_gb2(const float* __restrict__ x,
                                                   unsigned* __restrict__ mgb) {
    int xx = blockIdx.x * 256 + threadIdx.x;
    int y0 = blockIdx.y * 8;
    float rg[22], rb[22];
#pragma unroll
    for (int j = 0; j < 22; ++j) {
        int y = y0 + j - 7;
        int yc = min(max(y, 0), HH - 1);
        int i = yc * WW + xx;
        float g = x[HWSZ + i], b = x[2 * HWSZ + i];
        bool ok = (y >= 0) && (y < HH);
        rg[j] = ok ? g : 1e30f;
        rb[j] = ok ? b : 1e30f;
    }
    float sg[15], sb[15];
    sg[14] = rg[14]; sb[14] = rb[14];
#pragma unroll
    for (int j = 13; j >= 0; --j) {
        sg[j] = fminf(rg[j], sg[j + 1]);
        sb[j] = fminf(rb[j], sb[j + 1]);
    }
    float pg = 1e30f, pb = 1e30f;
#pragma unroll
    for (int j = 0; j < 8; ++j) {
        float mg = fminf(sg[j], pg), mb = fminf(sb[j], pb);
        mgb[(y0 + j) * WW + xx] = pbf2(mg, mb);
        if (j < 7) { pg = fminf(pg, rg[15 + j]); pb = fminf(pb, rb[15 + j]); }
    }
}

// ---------- horizontal 15-min of min(mgv,mbv) -> dc, fused histogram ----------
__global__ __launch_bounds__(256) void k_minh8_dc(const unsigned* __restrict__ mgb,
                                                  float* __restrict__ dc,
                                                  UdcpState* st) {
    __shared__ int h[NBINS];
    for (int j = threadIdx.x; j < NBINS; j += 256) h[j] = 0;
    __syncthreads();
    int row = blockIdx.x;
    int xb = threadIdx.x * 8;
    const unsigned* rp = mgb + row * WW;
    float r[22];
#pragma unroll
    for (int j = 0; j < 22; ++j) {
        int xc = min(max(xb + j - 7, 0), WW - 1);
        unsigned u = rp[xc];
        float v = fminf(ublo(u), ubhi(u));
        bool ok = (xb + j - 7 >= 0) && (xb + j - 7 < WW);
        r[j] = ok ? v : 1e30f;
    }
    float suf[15];
    suf[14] = r[14];
#pragma unroll
    for (int j = 13; j >= 0; --j) suf[j] = fminf(r[j], suf[j + 1]);
    float pre = 1e30f;
    float o[8];
#pragma unroll
    for (int j = 0; j < 8; ++j) {
        o[j] = fminf(suf[j], pre);
        if (j < 7) pre = fminf(pre, r[15 + j]);
    }
    float* dr = dc + row * WW + xb;
    *(float4*)dr = make_float4(o[0], o[1], o[2], o[3]);
    *(float4*)(dr + 4) = make_float4(o[4], o[5], o[6], o[7]);
#pragma unroll
    for (int j = 0; j < 8; ++j) {
        int b = (int)(o[j] * (float)NBINS);
        b = min(max(b, 0), NBINS - 1);
        atomicAdd(&h[b], 1);
    }
    __syncthreads();
    for (int j = threadIdx.x; j < NBINS; j += 256) {
        int v = h[j];
        if (v) atomicAdd(&st->hist[j], v);
    }
}

// ---------- k-th largest bin lower edge ----------
__global__ void k_tau(UdcpState* st) {
    __shared__ int csum[256];
    int tid = threadIdx.x;
    int hi = NBINS - 1 - 32 * tid;
    int local = 0;
    for (int k = 0; k < 32; ++k) local += st->hist[hi - k];
    csum[tid] = local;
    __syncthreads();
    if (tid == 0) {
        int cum = 0;
        float tau = 0.f;
        bool done = false;
        for (int c = 0; c < 256 && !done; ++c) {
            if (cum + csum[c] >= KTOP) {
                int h2 = NBINS - 1 - 32 * c;
                int cc = cum;
                for (int k = 0; k < 32; ++k) {
                    cc += st->hist[h2 - k];
                    if (cc >= KTOP) {
                        tau = (float)(h2 - k) / (float)NBINS;
                        done = true;
                        break;
                    }
                }
            } else {
                cum += csum[c];
            }
        }
        st->tau = tau;
    }
}

// ---------- atmospheric light: block-level reduce, few atomics ----------
__global__ __launch_bounds__(256) void k_A2(const float* __restrict__ dc,
                                            const float* __restrict__ x,
                                            UdcpState* st) {
    __shared__ float r0[256], r1[256], r2[256];
    __shared__ int anyflag;
    if (threadIdx.x == 0) anyflag = 0;
    __syncthreads();
    float tau = st->tau;
    const float4* dc4 = (const float4*)dc;
    int base4 = blockIdx.x * 1024;
    float m0 = -1e30f, m1 = -1e30f, m2 = -1e30f;
    bool found = false;
#pragma unroll
    for (int k = 0; k < 4; ++k) {
        int q = base4 + k * 256 + threadIdx.x;
        float4 v = dc4[q];
        float dv[4] = {v.x, v.y, v.z, v.w};
#pragma unroll
        for (int c = 0; c < 4; ++c) {
            if (dv[c] >= tau) {
                int i = q * 4 + c;
                m0 = fmaxf(m0, x[i]);
                m1 = fmaxf(m1, x[HWSZ + i]);
                m2 = fmaxf(m2, x[2 * HWSZ + i]);
                found = true;
            }
        }
    }
    if (found) anyflag = 1;
    __syncthreads();
    if (!anyflag) return;
    r0[threadIdx.x] = m0; r1[threadIdx.x] = m1; r2[threadIdx.x] = m2;
    __syncthreads();
    for (int s = 128; s > 0; s >>= 1) {
        if (threadIdx.x < s) {
            r0[threadIdx.x] = fmaxf(r0[threadIdx.x], r0[threadIdx.x + s]);
            r1[threadIdx.x] = fmaxf(r1[threadIdx.x], r1[threadIdx.x + s]);
            r2[threadIdx.x] = fmaxf(r2[threadIdx.x], r2[threadIdx.x + s]);
        }
        __syncthreads();
    }
    if (threadIdx.x == 0 && r0[0] > -1e29f) {
        atomicMax(&st->A_bits[0], __float_as_int(r0[0]));
        atomicMax(&st->A_bits[1], __float_as_int(r1[0]));
        atomicMax(&st->A_bits[2], __float_as_int(r2[0]));
    }
}

// ---------- fused: s from (mgv,mbv), h-min -> t, 121-box prefix on 4 fields ----------
__global__ __launch_bounds__(256) void k_boxh4f2(
        const float* __restrict__ x, const unsigned* __restrict__ mgb,
        const UdcpState* __restrict__ st, uint2* __restrict__ h4) {
    __shared__ float P0[WW], P1[WW], P2[WW], P3[WW];
    __shared__ float mrow[WW];
    __shared__ float wtot[4][4];
    int tid = threadIdx.x;
    int base = blockIdx.x * WW + tid * 8;
    int xb = tid * 8;
    float iA1 = 1.0f / __int_as_float(st->A_bits[1]);
    float iA2 = 1.0f / __int_as_float(st->A_bits[2]);
    {
        uint4 ua = *(const uint4*)(mgb + base);
        uint4 ub = *(const uint4*)(mgb + base + 4);
        unsigned uu[8] = {ua.x, ua.y, ua.z, ua.w, ub.x, ub.y, ub.z, ub.w};
#pragma unroll
        for (int j = 0; j < 8; ++j)
            mrow[xb + j] = fminf(ublo(uu[j]) * iA1, ubhi(uu[j]) * iA2);
    }
    float4 Ra = *(const float4*)(x + base), Rb = *(const float4*)(x + base + 4);
    float4 Ga = *(const float4*)(x + HWSZ + base), Gb = *(const float4*)(x + HWSZ + base + 4);
    float4 Ba = *(const float4*)(x + 2 * HWSZ + base), Bb = *(const float4*)(x + 2 * HWSZ + base + 4);
    float Rv[8] = {Ra.x, Ra.y, Ra.z, Ra.w, Rb.x, Rb.y, Rb.z, Rb.w};
    float Gv[8] = {Ga.x, Ga.y, Ga.z, Ga.w, Gb.x, Gb.y, Gb.z, Gb.w};
    float Bv[8] = {Ba.x, Ba.y, Ba.z, Ba.w, Bb.x, Bb.y, Bb.z, Bb.w};
    __syncthreads();
    // t = 1 - omega * horizontal 15-min of mrow (van Herk)
    float tv[8];
    {
        float r[22];
#pragma unroll
        for (int j = 0; j < 22; ++j) {
            int xc = min(max(xb + j - 7, 0), WW - 1);
            float v = mrow[xc];
            bool ok = (xb + j - 7 >= 0) && (xb + j - 7 < WW);
            r[j] = ok ? v : 1e30f;
        }
        float suf[15];
        suf[14] = r[14];
#pragma unroll
        for (int j = 13; j >= 0; --j) suf[j] = fminf(r[j], suf[j + 1]);
        float pre = 1e30f;
#pragma unroll
        for (int j = 0; j < 8; ++j) {
            tv[j] = 1.0f - OMEGA * fminf(suf[j], pre);
            if (j < 7) pre = fminf(pre, r[15 + j]);
        }
    }
    float gv[8];
#pragma unroll
    for (int j = 0; j < 8; ++j)
        gv[j] = 0.299f * Rv[j] + 0.587f * Gv[j] + 0.114f * Bv[j];
    float e0[8], e1[8], e2[8], e3[8];
    float s0 = 0.f, s1 = 0.f, s2 = 0.f, s3 = 0.f;
#pragma unroll
    for (int j = 0; j < 8; ++j) {
        s0 += gv[j]; e0[j] = s0;
        s1 += tv[j]; e1[j] = s1;
        s2 += gv[j] * tv[j]; e2[j] = s2;
        s3 += gv[j] * gv[j]; e3[j] = s3;
    }
    int lane = tid & 63, wv = tid >> 6;
    float i0 = s0, i1 = s1, i2 = s2, i3 = s3;
#pragma unroll
    for (int d = 1; d < 64; d <<= 1) {
        float u0 = __shfl_up(i0, d), u1 = __shfl_up(i1, d);
        float u2 = __shfl_up(i2, d), u3 = __shfl_up(i3, d);
        if (lane >= d) { i0 += u0; i1 += u1; i2 += u2; i3 += u3; }
    }
    if (lane == 63) {
        wtot[wv][0] = i0; wtot[wv][1] = i1; wtot[wv][2] = i2; wtot[wv][3] = i3;
    }
    __syncthreads();
    float off0 = i0 - s0, off1 = i1 - s1, off2 = i2 - s2, off3 = i3 - s3;
    for (int w = 0; w < wv; ++w) {
        off0 += wtot[w][0]; off1 += wtot[w][1];
        off2 += wtot[w][2]; off3 += wtot[w][3];
    }
#pragma unroll
    for (int j = 0; j < 8; ++j) {
        P0[xb + j] = e0[j] + off0;
        P1[xb + j] = e1[j] + off1;
        P2[xb + j] = e2[j] + off2;
        P3[xb + j] = e3[j] + off3;
    }
    __syncthreads();
#pragma unroll
    for (int j = 0; j < 8; ++j) {
        int xx = xb + j;
        int hi = min(xx + RBOX, WW - 1);
        int lo = xx - RBOX - 1;
        float b0 = 0.f, b1 = 0.f, b2 = 0.f, b3 = 0.f;
        if (lo >= 0) { b0 = P0[lo]; b1 = P1[lo]; b2 = P2[lo]; b3 = P3[lo]; }
        h4[base + j] = make_uint2(pbf2(P0[hi] - b0, P1[hi] - b1),
                                  pbf2(P2[hi] - b2, P3[hi] - b3));
    }
}

// ---------- vertical running-sum 121-box on packed fields + a/b ----------
__global__ __launch_bounds__(256) void k_boxv4(const uint2* __restrict__ h4,
                                               unsigned* __restrict__ ab) {
    int xx = blockIdx.x * 256 + threadIdx.x;
    int y0 = blockIdx.y * SEGV;
    float s0 = 0.f, s1 = 0.f, s2 = 0.f, s3 = 0.f;
#pragma unroll 4
    for (int j = 0; j <= 2 * RBOX; ++j) {
        int yy = y0 - RBOX + j;
        int yc = min(max(yy, 0), HH - 1);
        uint2 v = h4[yc * WW + xx];
        bool ok = (yy >= 0) && (yy < HH);
        s0 += ok ? ublo(v.x) : 0.f;
        s1 += ok ? ubhi(v.x) : 0.f;
        s2 += ok ? ublo(v.y) : 0.f;
        s3 += ok ? ubhi(v.y) : 0.f;
    }
    float cx = (float)(min(xx + RBOX, WW - 1) - max(xx - RBOX, 0) + 1);
#pragma unroll
    for (int k = 0; k < SEGV; ++k) {
        int y = y0 + k;
        float cy = (float)(min(y + RBOX, HH - 1) - max(y - RBOX, 0) + 1);
        float inv = 1.0f / (cy * cx);
        float mI = s0 * inv, mp = s1 * inv;
        float cov = s2 * inv - mI * mp;
        float var = s3 * inv - mI * mI;
        float av = cov / (var + GFEPS);
        ab[y * WW + xx] = pbf2(av, mp - av * mI);
        int ya = y + RBOX + 1, ys = y - RBOX;
        int yac = min(ya, HH - 1), ysc = max(ys, 0);
        uint2 va = h4[yac * WW + xx];
        uint2 vs = h4[ysc * WW + xx];
        bool oa = ya < HH, os = ys >= 0;
        float a0 = oa ? ublo(va.x) : 0.f, a1 = oa ? ubhi(va.x) : 0.f;
        float a2 = oa ? ublo(va.y) : 0.f, a3 = oa ? ubhi(va.y) : 0.f;
        float d0 = os ? ublo(vs.x) : 0.f, d1 = os ? ubhi(vs.x) : 0.f;
        float d2 = os ? ublo(vs.y) : 0.f, d3 = os ? ubhi(vs.y) : 0.f;
        s0 += a0 - d0; s1 += a1 - d1; s2 += a2 - d2; s3 += a3 - d3;
    }
}

// ---------- horizontal 121-box on packed (a,b) via LDS prefix sum ----------
__global__ __launch_bounds__(256) void k_boxh2_ps(const unsigned* __restrict__ ab,
                                                  unsigned* __restrict__ hab) {
    __shared__ float P0[WW], P1[WW];
    __shared__ float wtot[4][2];
    int tid = threadIdx.x;
    int base = blockIdx.x * WW + tid * 8;
    uint4 q0 = *(const uint4*)(ab + base);
    uint4 q1 = *(const uint4*)(ab + base + 4);
    unsigned uu[8] = {q0.x, q0.y, q0.z, q0.w, q1.x, q1.y, q1.z, q1.w};
    float e0[8], e1[8];
    float s0 = 0.f, s1 = 0.f;
#pragma unroll
    for (int j = 0; j < 8; ++j) {
        s0 += ublo(uu[j]); e0[j] = s0;
        s1 += ubhi(uu[j]); e1[j] = s1;
    }
    int lane = tid & 63, wv = tid >> 6;
    float i0 = s0, i1 = s1;
#pragma unroll
    for (int d = 1; d < 64; d <<= 1) {
        float u0 = __shfl_up(i0, d), u1 = __shfl_up(i1, d);
        if (lane >= d) { i0 += u0; i1 += u1; }
    }
    if (lane == 63) { wtot[wv][0] = i0; wtot[wv][1] = i1; }
    __syncthreads();
    float off0 = i0 - s0, off1 = i1 - s1;
    for (int w = 0; w < wv; ++w) { off0 += wtot[w][0]; off1 += wtot[w][1]; }
    int xb = tid * 8;
#pragma unroll
    for (int j = 0; j < 8; ++j) {
        P0[xb + j] = e0[j] + off0;
        P1[xb + j] = e1[j] + off1;
    }
    __syncthreads();
#pragma unroll
    for (int j = 0; j < 8; ++j) {
        int xx = xb + j;
        int hi = min(xx + RBOX, WW - 1);
        int lo = xx - RBOX - 1;
        float b0 = 0.f, b1 = 0.f;
        if (lo >= 0) { b0 = P0[lo]; b1 = P1[lo]; }
        hab[base + j] = pbf2(P0[hi] - b0, P1[hi] - b1);
    }
}

// ---------- vertical running-sum 121-box on packed (a,b) + recovery ----------
__global__ __launch_bounds__(256) void k_final_rs(const unsigned* __restrict__ hab,
                                                  const float* __restrict__ x,
                                                  const UdcpState* __restrict__ st,
                                                  float* __restrict__ out) {
    int xx = blockIdx.x * 256 + threadIdx.x;
    int y0 = blockIdx.y * SEGV;
    float A0 = __int_as_float(st->A_bits[0]);
    float A1 = __int_as_float(st->A_bits[1]);
    float A2 = __int_as_float(st->A_bits[2]);
    float s0 = 0.f, s1 = 0.f;
#pragma unroll 4
    for (int j = 0; j <= 2 * RBOX; ++j) {
        int yy = y0 - RBOX + j;
        int yc = min(max(yy, 0), HH - 1);
        unsigned v = hab[yc * WW + xx];
        bool ok = (yy >= 0) && (yy < HH);
        s0 += ok ? ublo(v) : 0.f;
        s1 += ok ? ubhi(v) : 0.f;
    }
    float cx = (float)(min(xx + RBOX, WW - 1) - max(xx - RBOX, 0) + 1);
#pragma unroll
    for (int k = 0; k < SEGV; ++k) {
        int y = y0 + k;
        float cy = (float)(min(y + RBOX, HH - 1) - max(y - RBOX, 0) + 1);
        float inv = 1.0f / (cy * cx);
        int i = y * WW + xx;
        float R = x[i], G = x[HWSZ + i], B = x[2 * HWSZ + i];
        float guide = 0.299f * R + 0.587f * G + 0.114f * B;
        float q = s0 * inv * guide + s1 * inv;
        float invt = 1.0f / fmaxf(q, T0C);
        float J0 = (R - A0) * invt + A0;
        float J1 = (G - A1) * invt + A1;
        float J2 = (B - A2) * invt + A2;
        out[i] = fminf(fmaxf(J0, 0.f), 1.f);
        out[HWSZ + i] = fminf(fmaxf(J1, 0.f), 1.f);
        out[2 * HWSZ + i] = fminf(fmaxf(J2, 0.f), 1.f);
        int ya = y + RBOX + 1, ys = y - RBOX;
        int yac = min(ya, HH - 1), ysc = max(ys, 0);
        unsigned va = hab[yac * WW + xx];
        unsigned vs = hab[ysc * WW + xx];
        bool oa = ya < HH, os = ys >= 0;
        float a0 = oa ? ublo(va) : 0.f, a1 = oa ? ubhi(va) : 0.f;
        float d0 = os ? ublo(vs) : 0.f, d1 = os ? ubhi(vs) : 0.f;
        s0 += a0 - d0; s1 += a1 - d1;
    }
}

extern "C" void kernel_launch(void* const* d_in, const int* in_sizes, int n_in,
                              void* d_out, int out_size, void* d_ws, size_t ws_size,
                              hipStream_t stream) {
    const float* x = (const float*)d_in[0];
    float* out = (float*)d_out;
    char* ws = (char*)d_ws;
    UdcpState* st = (UdcpState*)ws;
    unsigned* MGB = (unsigned*)(ws + 65536);          // 16 MB
    float* DC = (float*)(MGB + HWSZ);                 // 16 MB
    uint2* H4 = (uint2*)(DC + HWSZ);                  // 32 MB
    unsigned* AB = (unsigned*)(H4 + HWSZ);            // 16 MB
    unsigned* HAB = AB + HWSZ;                        // 16 MB

    hipMemsetAsync(st, 0, sizeof(UdcpState), stream);

    dim3 blk(256);
    dim3 mgrid(WW / 256, HH / 8);
    dim3 vgrid(WW / 256, HH / SEGV);

    // dark channel + histogram + A
    k_minv8_gb2<<<mgrid, blk, 0, stream>>>(x, MGB);
    k_minh8_dc<<<HH, blk, 0, stream>>>(MGB, DC, st);
    k_tau<<<1, blk, 0, stream>>>(st);
    k_A2<<<HWSZ / 4096, blk, 0, stream>>>(DC, x, st);

    // guided filter (t computed inline from MGB)
    k_boxh4f2<<<HH, blk, 0, stream>>>(x, MGB, st, H4);
    k_boxv4<<<vgrid, blk, 0, stream>>>(H4, AB);
    k_boxh2_ps<<<HH, blk, 0, stream>>>(AB, HAB);
    k_final_rs<<<vgrid, blk, 0, stream>>>(HAB, x, st, out);
}

// Round 6
// 199.316 us; speedup vs baseline: 5.1119x; 1.1552x over previous
//
#include <hip/hip_runtime.h>
#include <math.h>

#define HH 2048
#define WW 2048
#define HWSZ (HH*WW)
#define RBOX 60
#define NBINS 2048
#define KTOP 4194
#define OMEGA 0.95f
#define T0C 0.1f
#define GFEPS 1e-4f
#define SEGV 16

struct UdcpState {
    int hist[NBINS];
    float tau;
    int A_bits[3];
};

// bf16 pair pack (round-to-nearest-even; truncation would bias cov -> bad a)
__device__ __forceinline__ unsigned pbf2(float lo, float hi) {
    unsigned ul = __float_as_uint(lo), uh = __float_as_uint(hi);
    ul += 0x7FFFu + ((ul >> 16) & 1u);
    uh += 0x7FFFu + ((uh >> 16) & 1u);
    return (ul >> 16) | (uh & 0xFFFF0000u);
}
__device__ __forceinline__ float ublo(unsigned u) { return __uint_as_float(u << 16); }
__device__ __forceinline__ float ubhi(unsigned u) { return __uint_as_float(u & 0xFFFF0000u); }

// ---------- vertical 15-min of G and B separately -> packed bf16 pair ----------
__global__ __launch_bounds__(256) void k_minv8_gb2(const float* __restrict__ x,
                                                   unsigned* __restrict__ mgb) {
    int xx = blockIdx.x * 256 + threadIdx.x;
    int y0 = blockIdx.y * 8;
    float rg[22], rb[22];
#pragma unroll
    for (int j = 0; j < 22; ++j) {
        int y = y0 + j - 7;
        int yc = min(max(y, 0), HH - 1);
        int i = yc * WW + xx;
        float g = x[HWSZ + i], b = x[2 * HWSZ + i];
        bool ok = (y >= 0) && (y < HH);
        rg[j] = ok ? g : 1e30f;
        rb[j] = ok ? b : 1e30f;
    }
    float sg[15], sb[15];
    sg[14] = rg[14]; sb[14] = rb[14];
#pragma unroll
    for (int j = 13; j >= 0; --j) {
        sg[j] = fminf(rg[j], sg[j + 1]);
        sb[j] = fminf(rb[j], sb[j + 1]);
    }
    float pg = 1e30f, pb = 1e30f;
#pragma unroll
    for (int j = 0; j < 8; ++j) {
        float mg = fminf(sg[j], pg), mb = fminf(sb[j], pb);
        mgb[(y0 + j) * WW + xx] = pbf2(mg, mb);
        if (j < 7) { pg = fminf(pg, rg[15 + j]); pb = fminf(pb, rb[15 + j]); }
    }
}

// ---------- horizontal 15-min of min(mgv,mbv) -> dc, fused histogram ----------
__global__ __launch_bounds__(256) void k_minh8_dc(const unsigned* __restrict__ mgb,
                                                  float* __restrict__ dc,
                                                  UdcpState* st) {
    __shared__ int h[NBINS];
    for (int j = threadIdx.x; j < NBINS; j += 256) h[j] = 0;
    __syncthreads();
    int row = blockIdx.x;
    int xb = threadIdx.x * 8;
    const unsigned* rp = mgb + row * WW;
    float r[22];
#pragma unroll
    for (int j = 0; j < 22; ++j) {
        int xc = min(max(xb + j - 7, 0), WW - 1);
        unsigned u = rp[xc];
        float v = fminf(ublo(u), ubhi(u));
        bool ok = (xb + j - 7 >= 0) && (xb + j - 7 < WW);
        r[j] = ok ? v : 1e30f;
    }
    float suf[15];
    suf[14] = r[14];
#pragma unroll
    for (int j = 13; j >= 0; --j) suf[j] = fminf(r[j], suf[j + 1]);
    float pre = 1e30f;
    float o[8];
#pragma unroll
    for (int j = 0; j < 8; ++j) {
        o[j] = fminf(suf[j], pre);
        if (j < 7) pre = fminf(pre, r[15 + j]);
    }
    float* dr = dc + row * WW + xb;
    *(float4*)dr = make_float4(o[0], o[1], o[2], o[3]);
    *(float4*)(dr + 4) = make_float4(o[4], o[5], o[6], o[7]);
#pragma unroll
    for (int j = 0; j < 8; ++j) {
        int b = (int)(o[j] * (float)NBINS);
        b = min(max(b, 0), NBINS - 1);
        atomicAdd(&h[b], 1);
    }
    __syncthreads();
    for (int j = threadIdx.x; j < NBINS; j += 256) {
        int v = h[j];
        if (v) atomicAdd(&st->hist[j], v);
    }
}

// ---------- k-th largest bin lower edge ----------
__global__ void k_tau(UdcpState* st) {
    __shared__ int csum[256];
    int tid = threadIdx.x;
    int hi = NBINS - 1 - 8 * tid;
    int local = 0;
    for (int k = 0; k < 8; ++k) local += st->hist[hi - k];
    csum[tid] = local;
    __syncthreads();
    if (tid == 0) {
        int cum = 0;
        float tau = 0.f;
        bool done = false;
        for (int c = 0; c < 256 && !done; ++c) {
            if (cum + csum[c] >= KTOP) {
                int h2 = NBINS - 1 - 8 * c;
                int cc = cum;
                for (int k = 0; k < 8; ++k) {
                    cc += st->hist[h2 - k];
                    if (cc >= KTOP) {
                        tau = (float)(h2 - k) / (float)NBINS;
                        done = true;
                        break;
                    }
                }
            } else {
                cum += csum[c];
            }
        }
        st->tau = tau;
    }
}

// ---------- atmospheric light: block-level reduce, few atomics ----------
__global__ __launch_bounds__(256) void k_A2(const float* __restrict__ dc,
                                            const float* __restrict__ x,
                                            UdcpState* st) {
    __shared__ float r0[256], r1[256], r2[256];
    __shared__ int anyflag;
    if (threadIdx.x == 0) anyflag = 0;
    __syncthreads();
    float tau = st->tau;
    const float4* dc4 = (const float4*)dc;
    int base4 = blockIdx.x * 1024;
    float m0 = -1e30f, m1 = -1e30f, m2 = -1e30f;
    bool found = false;
#pragma unroll
    for (int k = 0; k < 4; ++k) {
        int q = base4 + k * 256 + threadIdx.x;
        float4 v = dc4[q];
        float dv[4] = {v.x, v.y, v.z, v.w};
#pragma unroll
        for (int c = 0; c < 4; ++c) {
            if (dv[c] >= tau) {
                int i = q * 4 + c;
                m0 = fmaxf(m0, x[i]);
                m1 = fmaxf(m1, x[HWSZ + i]);
                m2 = fmaxf(m2, x[2 * HWSZ + i]);
                found = true;
            }
        }
    }
    if (found) anyflag = 1;
    __syncthreads();
    if (!anyflag) return;
    r0[threadIdx.x] = m0; r1[threadIdx.x] = m1; r2[threadIdx.x] = m2;
    __syncthreads();
    for (int s = 128; s > 0; s >>= 1) {
        if (threadIdx.x < s) {
            r0[threadIdx.x] = fmaxf(r0[threadIdx.x], r0[threadIdx.x + s]);
            r1[threadIdx.x] = fmaxf(r1[threadIdx.x], r1[threadIdx.x + s]);
            r2[threadIdx.x] = fmaxf(r2[threadIdx.x], r2[threadIdx.x + s]);
        }
        __syncthreads();
    }
    if (threadIdx.x == 0 && r0[0] > -1e29f) {
        atomicMax(&st->A_bits[0], __float_as_int(r0[0]));
        atomicMax(&st->A_bits[1], __float_as_int(r1[0]));
        atomicMax(&st->A_bits[2], __float_as_int(r2[0]));
    }
}

// ---------- fused: s from (mgv,mbv), h-min -> t, 121-box prefix on 4 fields ----------
__global__ __launch_bounds__(256) void k_boxh4f2(
        const float* __restrict__ x, const unsigned* __restrict__ mgb,
        const UdcpState* __restrict__ st, uint2* __restrict__ h4) {
    __shared__ float P0[WW], P1[WW], P2[WW], P3[WW];
    __shared__ float mrow[WW];
    __shared__ float wtot[4][4];
    int tid = threadIdx.x;
    int base = blockIdx.x * WW + tid * 8;
    int xb = tid * 8;
    float iA1 = 1.0f / __int_as_float(st->A_bits[1]);
    float iA2 = 1.0f / __int_as_float(st->A_bits[2]);
    {
        uint4 ua = *(const uint4*)(mgb + base);
        uint4 ub = *(const uint4*)(mgb + base + 4);
        unsigned uu[8] = {ua.x, ua.y, ua.z, ua.w, ub.x, ub.y, ub.z, ub.w};
#pragma unroll
        for (int j = 0; j < 8; ++j)
            mrow[xb + j] = fminf(ublo(uu[j]) * iA1, ubhi(uu[j]) * iA2);
    }
    float4 Ra = *(const float4*)(x + base), Rb = *(const float4*)(x + base + 4);
    float4 Ga = *(const float4*)(x + HWSZ + base), Gb = *(const float4*)(x + HWSZ + base + 4);
    float4 Ba = *(const float4*)(x + 2 * HWSZ + base), Bb = *(const float4*)(x + 2 * HWSZ + base + 4);
    float Rv[8] = {Ra.x, Ra.y, Ra.z, Ra.w, Rb.x, Rb.y, Rb.z, Rb.w};
    float Gv[8] = {Ga.x, Ga.y, Ga.z, Ga.w, Gb.x, Gb.y, Gb.z, Gb.w};
    float Bv[8] = {Ba.x, Ba.y, Ba.z, Ba.w, Bb.x, Bb.y, Bb.z, Bb.w};
    __syncthreads();
    float tv[8];
    {
        float r[22];
#pragma unroll
        for (int j = 0; j < 22; ++j) {
            int xc = min(max(xb + j - 7, 0), WW - 1);
            float v = mrow[xc];
            bool ok = (xb + j - 7 >= 0) && (xb + j - 7 < WW);
            r[j] = ok ? v : 1e30f;
        }
        float suf[15];
        suf[14] = r[14];
#pragma unroll
        for (int j = 13; j >= 0; --j) suf[j] = fminf(r[j], suf[j + 1]);
        float pre = 1e30f;
#pragma unroll
        for (int j = 0; j < 8; ++j) {
            tv[j] = 1.0f - OMEGA * fminf(suf[j], pre);
            if (j < 7) pre = fminf(pre, r[15 + j]);
        }
    }
    float gv[8];
#pragma unroll
    for (int j = 0; j < 8; ++j)
        gv[j] = 0.299f * Rv[j] + 0.587f * Gv[j] + 0.114f * Bv[j];
    float e0[8], e1[8], e2[8], e3[8];
    float s0 = 0.f, s1 = 0.f, s2 = 0.f, s3 = 0.f;
#pragma unroll
    for (int j = 0; j < 8; ++j) {
        s0 += gv[j]; e0[j] = s0;
        s1 += tv[j]; e1[j] = s1;
        s2 += gv[j] * tv[j]; e2[j] = s2;
        s3 += gv[j] * gv[j]; e3[j] = s3;
    }
    int lane = tid & 63, wv = tid >> 6;
    float i0 = s0, i1 = s1, i2 = s2, i3 = s3;
#pragma unroll
    for (int d = 1; d < 64; d <<= 1) {
        float u0 = __shfl_up(i0, d), u1 = __shfl_up(i1, d);
        float u2 = __shfl_up(i2, d), u3 = __shfl_up(i3, d);
        if (lane >= d) { i0 += u0; i1 += u1; i2 += u2; i3 += u3; }
    }
    if (lane == 63) {
        wtot[wv][0] = i0; wtot[wv][1] = i1; wtot[wv][2] = i2; wtot[wv][3] = i3;
    }
    __syncthreads();
    float off0 = i0 - s0, off1 = i1 - s1, off2 = i2 - s2, off3 = i3 - s3;
    for (int w = 0; w < wv; ++w) {
        off0 += wtot[w][0]; off1 += wtot[w][1];
        off2 += wtot[w][2]; off3 += wtot[w][3];
    }
#pragma unroll
    for (int j = 0; j < 8; ++j) {
        P0[xb + j] = e0[j] + off0;
        P1[xb + j] = e1[j] + off1;
        P2[xb + j] = e2[j] + off2;
        P3[xb + j] = e3[j] + off3;
    }
    __syncthreads();
#pragma unroll
    for (int j = 0; j < 8; ++j) {
        int xx = xb + j;
        int hi = min(xx + RBOX, WW - 1);
        int lo = xx - RBOX - 1;
        float b0 = 0.f, b1 = 0.f, b2 = 0.f, b3 = 0.f;
        if (lo >= 0) { b0 = P0[lo]; b1 = P1[lo]; b2 = P2[lo]; b3 = P3[lo]; }
        h4[base + j] = make_uint2(pbf2(P0[hi] - b0, P1[hi] - b1),
                                  pbf2(P2[hi] - b2, P3[hi] - b3));
    }
}

// ---------- vertical running-sum 121-box on packed fields + a/b ----------
// SEGV=16, grid 1024 blocks; add/sub rows batch-loaded into registers first
__global__ __launch_bounds__(256) void k_boxv4(const uint2* __restrict__ h4,
                                               unsigned* __restrict__ ab) {
    int xx = blockIdx.x * 256 + threadIdx.x;
    int y0 = blockIdx.y * SEGV;
    float s0, s1, s2, s3;
    {
        float p0 = 0.f, p1 = 0.f, p2 = 0.f, p3 = 0.f;
        float q0 = 0.f, q1 = 0.f, q2 = 0.f, q3 = 0.f;
#pragma unroll 8
        for (int j = 0; j <= 2 * RBOX; ++j) {
            int yy = y0 - RBOX + j;
            int yc = min(max(yy, 0), HH - 1);
            uint2 v = h4[yc * WW + xx];
            bool ok = (yy >= 0) && (yy < HH);
            if (j & 1) {
                p0 += ok ? ublo(v.x) : 0.f; p1 += ok ? ubhi(v.x) : 0.f;
                p2 += ok ? ublo(v.y) : 0.f; p3 += ok ? ubhi(v.y) : 0.f;
            } else {
                q0 += ok ? ublo(v.x) : 0.f; q1 += ok ? ubhi(v.x) : 0.f;
                q2 += ok ? ublo(v.y) : 0.f; q3 += ok ? ubhi(v.y) : 0.f;
            }
        }
        s0 = p0 + q0; s1 = p1 + q1; s2 = p2 + q2; s3 = p3 + q3;
    }
    // batch-load all add/sub rows (compile-time indices -> registers)
    uint2 VA[SEGV], VS[SEGV];
#pragma unroll
    for (int k = 0; k < SEGV; ++k) {
        int ya = y0 + k + RBOX + 1, ys = y0 + k - RBOX;
        VA[k] = h4[min(ya, HH - 1) * WW + xx];
        VS[k] = h4[max(ys, 0) * WW + xx];
    }
    float cx = (float)(min(xx + RBOX, WW - 1) - max(xx - RBOX, 0) + 1);
#pragma unroll
    for (int k = 0; k < SEGV; ++k) {
        int y = y0 + k;
        float cy = (float)(min(y + RBOX, HH - 1) - max(y - RBOX, 0) + 1);
        float inv = 1.0f / (cy * cx);
        float mI = s0 * inv, mp = s1 * inv;
        float cov = s2 * inv - mI * mp;
        float var = s3 * inv - mI * mI;
        float av = cov / (var + GFEPS);
        ab[y * WW + xx] = pbf2(av, mp - av * mI);
        int ya = y + RBOX + 1, ys = y - RBOX;
        bool oa = ya < HH, os = ys >= 0;
        s0 += (oa ? ublo(VA[k].x) : 0.f) - (os ? ublo(VS[k].x) : 0.f);
        s1 += (oa ? ubhi(VA[k].x) : 0.f) - (os ? ubhi(VS[k].x) : 0.f);
        s2 += (oa ? ublo(VA[k].y) : 0.f) - (os ? ublo(VS[k].y) : 0.f);
        s3 += (oa ? ubhi(VA[k].y) : 0.f) - (os ? ubhi(VS[k].y) : 0.f);
    }
}

// ---------- horizontal 121-box on packed (a,b) via LDS prefix sum ----------
__global__ __launch_bounds__(256) void k_boxh2_ps(const unsigned* __restrict__ ab,
                                                  unsigned* __restrict__ hab) {
    __shared__ float P0[WW], P1[WW];
    __shared__ float wtot[4][2];
    int tid = threadIdx.x;
    int base = blockIdx.x * WW + tid * 8;
    uint4 q0 = *(const uint4*)(ab + base);
    uint4 q1 = *(const uint4*)(ab + base + 4);
    unsigned uu[8] = {q0.x, q0.y, q0.z, q0.w, q1.x, q1.y, q1.z, q1.w};
    float e0[8], e1[8];
    float s0 = 0.f, s1 = 0.f;
#pragma unroll
    for (int j = 0; j < 8; ++j) {
        s0 += ublo(uu[j]); e0[j] = s0;
        s1 += ubhi(uu[j]); e1[j] = s1;
    }
    int lane = tid & 63, wv = tid >> 6;
    float i0 = s0, i1 = s1;
#pragma unroll
    for (int d = 1; d < 64; d <<= 1) {
        float u0 = __shfl_up(i0, d), u1 = __shfl_up(i1, d);
        if (lane >= d) { i0 += u0; i1 += u1; }
    }
    if (lane == 63) { wtot[wv][0] = i0; wtot[wv][1] = i1; }
    __syncthreads();
    float off0 = i0 - s0, off1 = i1 - s1;
    for (int w = 0; w < wv; ++w) { off0 += wtot[w][0]; off1 += wtot[w][1]; }
    int xb = tid * 8;
#pragma unroll
    for (int j = 0; j < 8; ++j) {
        P0[xb + j] = e0[j] + off0;
        P1[xb + j] = e1[j] + off1;
    }
    __syncthreads();
#pragma unroll
    for (int j = 0; j < 8; ++j) {
        int xx = xb + j;
        int hi = min(xx + RBOX, WW - 1);
        int lo = xx - RBOX - 1;
        float b0 = 0.f, b1 = 0.f;
        if (lo >= 0) { b0 = P0[lo]; b1 = P1[lo]; }
        hab[base + j] = pbf2(P0[hi] - b0, P1[hi] - b1);
    }
}

// ---------- vertical running-sum 121-box on packed (a,b) + recovery ----------
// SEGV=16; hab add/sub batch-loaded; x rolling depth-1 prefetch; NT out stores
__global__ __launch_bounds__(256) void k_final_rs(const unsigned* __restrict__ hab,
                                                  const float* __restrict__ x,
                                                  const UdcpState* __restrict__ st,
                                                  float* __restrict__ out) {
    int xx = blockIdx.x * 256 + threadIdx.x;
    int y0 = blockIdx.y * SEGV;
    float A0 = __int_as_float(st->A_bits[0]);
    float A1 = __int_as_float(st->A_bits[1]);
    float A2 = __int_as_float(st->A_bits[2]);
    float s0, s1;
    {
        float p0 = 0.f, p1 = 0.f, q0 = 0.f, q1 = 0.f;
#pragma unroll 8
        for (int j = 0; j <= 2 * RBOX; ++j) {
            int yy = y0 - RBOX + j;
            int yc = min(max(yy, 0), HH - 1);
            unsigned v = hab[yc * WW + xx];
            bool ok = (yy >= 0) && (yy < HH);
            if (j & 1) { p0 += ok ? ublo(v) : 0.f; p1 += ok ? ubhi(v) : 0.f; }
            else       { q0 += ok ? ublo(v) : 0.f; q1 += ok ? ubhi(v) : 0.f; }
        }
        s0 = p0 + q0; s1 = p1 + q1;
    }
    unsigned VA[SEGV], VS[SEGV];
#pragma unroll
    for (int k = 0; k < SEGV; ++k) {
        int ya = y0 + k + RBOX + 1, ys = y0 + k - RBOX;
        VA[k] = hab[min(ya, HH - 1) * WW + xx];
        VS[k] = hab[max(ys, 0) * WW + xx];
    }
    float cx = (float)(min(xx + RBOX, WW - 1) - max(xx - RBOX, 0) + 1);
    int i0 = y0 * WW + xx;
    float R = x[i0], G = x[HWSZ + i0], B = x[2 * HWSZ + i0];
#pragma unroll
    for (int k = 0; k < SEGV; ++k) {
        int y = y0 + k;
        int i = y * WW + xx;
        float Rn, Gn, Bn;
        if (k < SEGV - 1) {
            Rn = x[i + WW]; Gn = x[HWSZ + i + WW]; Bn = x[2 * HWSZ + i + WW];
        }
        float cy = (float)(min(y + RBOX, HH - 1) - max(y - RBOX, 0) + 1);
        float inv = 1.0f / (cy * cx);
        float guide = 0.299f * R + 0.587f * G + 0.114f * B;
        float q = s0 * inv * guide + s1 * inv;
        float invt = 1.0f / fmaxf(q, T0C);
        float J0 = (R - A0) * invt + A0;
        float J1 = (G - A1) * invt + A1;
        float J2 = (B - A2) * invt + A2;
        __builtin_nontemporal_store(fminf(fmaxf(J0, 0.f), 1.f), &out[i]);
        __builtin_nontemporal_store(fminf(fmaxf(J1, 0.f), 1.f), &out[HWSZ + i]);
        __builtin_nontemporal_store(fminf(fmaxf(J2, 0.f), 1.f), &out[2 * HWSZ + i]);
        int ya = y + RBOX + 1, ys = y - RBOX;
        bool oa = ya < HH, os = ys >= 0;
        s0 += (oa ? ublo(VA[k]) : 0.f) - (os ? ublo(VS[k]) : 0.f);
        s1 += (oa ? ubhi(VA[k]) : 0.f) - (os ? ubhi(VS[k]) : 0.f);
        if (k < SEGV - 1) { R = Rn; G = Gn; B = Bn; }
    }
}

extern "C" void kernel_launch(void* const* d_in, const int* in_sizes, int n_in,
                              void* d_out, int out_size, void* d_ws, size_t ws_size,
                              hipStream_t stream) {
    const float* x = (const float*)d_in[0];
    float* out = (float*)d_out;
    char* ws = (char*)d_ws;
    UdcpState* st = (UdcpState*)ws;
    unsigned* MGB = (unsigned*)(ws + 65536);          // 16 MB
    float* DC = (float*)(MGB + HWSZ);                 // 16 MB
    uint2* H4 = (uint2*)(DC + HWSZ);                  // 32 MB
    unsigned* AB = (unsigned*)(H4 + HWSZ);            // 16 MB
    unsigned* HAB = AB + HWSZ;                        // 16 MB

    hipMemsetAsync(st, 0, sizeof(UdcpState), stream);

    dim3 blk(256);
    dim3 mgrid(WW / 256, HH / 8);
    dim3 vgrid(WW / 256, HH / SEGV);

    // dark channel + histogram + A
    k_minv8_gb2<<<mgrid, blk, 0, stream>>>(x, MGB);
    k_minh8_dc<<<HH, blk, 0, stream>>>(MGB, DC, st);
    k_tau<<<1, blk, 0, stream>>>(st);
    k_A2<<<HWSZ / 4096, blk, 0, stream>>>(DC, x, st);

    // guided filter (t computed inline from MGB)
    k_boxh4f2<<<HH, blk, 0, stream>>>(x, MGB, st, H4);
    k_boxv4<<<vgrid, blk, 0, stream>>>(H4, AB);
    k_boxh2_ps<<<HH, blk, 0, stream>>>(AB, HAB);
    k_final_rs<<<vgrid, blk, 0, stream>>>(HAB, x, st, out);
}